// Round 3
// baseline (306.559 us; speedup 1.0000x reference)
//
#include <hip/hip_runtime.h>

typedef unsigned short u16;
typedef __attribute__((ext_vector_type(8))) _Float16 f16x8;
typedef __attribute__((ext_vector_type(4))) float f32x4;

#define MFMA_F16 __builtin_amdgcn_mfma_f32_16x16x32_f16

static __device__ __forceinline__ u16 f2h(float f) {
    return __builtin_bit_cast(u16, (_Float16)f);
}
static __device__ __forceinline__ ushort4 f4_to_h4(const float4 v) {
    ushort4 r;
    r.x = f2h(v.x); r.y = f2h(v.y); r.z = f2h(v.z); r.w = f2h(v.w);
    return r;
}

// ---------------------------------------------------------------------------
// Kernel 0: prep_w — convert Wq/Wk/Wv/Wo (4 x 16384 float4) fp32 -> fp16.
// ---------------------------------------------------------------------------
__global__ __launch_bounds__(256) void prep_w(
    const float* __restrict__ wq, const float* __restrict__ wk,
    const float* __restrict__ wv, const float* __restrict__ wo,
    u16* __restrict__ w4)
{
    const int tid = blockIdx.x * 256 + threadIdx.x;   // 16384 threads
    for (int i = tid; i < 65536; i += 16384) {
        const float* src = (i < 16384) ? wq : (i < 32768) ? wk
                         : (i < 49152) ? wv : wo;
        ((ushort4*)w4)[i] = f4_to_h4(((const float4*)src)[i & 16383]);
    }
}

// ---------------------------------------------------------------------------
// Kernel 1: Q/K/V projection, fp16 MFMA.
// R15: T14 issue-early/write-late — next-kc global loads are issued before
// the MFMA phase so ~400cy of load latency hides under compute; the LDS
// writes (and their vmcnt drain) move to after the post-compute barrier.
// ---------------------------------------------------------------------------
__global__ __launch_bounds__(256) void proj_qkv(
    const float* __restrict__ X, const u16* __restrict__ w4,
    const float* __restrict__ bq, const float* __restrict__ bk,
    const float* __restrict__ bv,
    u16* __restrict__ Qh, u16* __restrict__ Kh, u16* __restrict__ Vt)
{
    const int z = blockIdx.y;
    const u16* __restrict__ W     = w4 + z * 65536;
    const float* __restrict__ bias = (z == 0) ? bq : (z == 1) ? bk : bv;

    const int m0   = blockIdx.x * 64;          // global row (b*2048 + n0)
    const int t    = threadIdx.x;
    const int w    = t >> 6;
    const int lane = t & 63;
    const int quad = lane >> 4;
    const int l16  = lane & 15;

    __shared__ __align__(16) u16 smem[18432];  // 36864 B
    u16* Xs = smem;            // 64 x 40 during k-loop
    u16* Ws = smem + 2560;     // 256 x 40 during k-loop

    f32x4 acc[16];
#pragma unroll
    for (int i = 0; i < 16; ++i) acc[i] = f32x4{0.f, 0.f, 0.f, 0.f};

    float4 xst[2];
    int4   wst[4];
    // prologue: stage kc=0
#pragma unroll
    for (int i = 0; i < 2; ++i) {
        const int ch = i * 256 + t;
        const int row = ch >> 3, cg = ch & 7;
        xst[i] = *(const float4*)&X[(size_t)(m0 + row) * 256 + cg * 4];
    }
#pragma unroll
    for (int i = 0; i < 4; ++i) {
        const int ch = i * 256 + t;
        const int row = ch >> 2, cg = ch & 3;
        wst[i] = *(const int4*)&W[(size_t)row * 256 + cg * 8];
    }
#pragma unroll
    for (int i = 0; i < 2; ++i) {
        const int ch = i * 256 + t;
        const int row = ch >> 3, cg = ch & 7;
        *(ushort4*)&Xs[row * 40 + cg * 4] = f4_to_h4(xst[i]);
    }
#pragma unroll
    for (int i = 0; i < 4; ++i) {
        const int ch = i * 256 + t;
        const int row = ch >> 2, cg = ch & 3;
        *(int4*)&Ws[row * 40 + cg * 8] = wst[i];
    }
    __syncthreads();

    for (int kc = 0; kc < 8; ++kc) {
        const bool hasnext = (kc < 7);
        if (hasnext) {
            const int kn = kc + 1;
#pragma unroll
            for (int i = 0; i < 2; ++i) {
                const int ch = i * 256 + t;
                const int row = ch >> 3, cg = ch & 7;
                xst[i] = *(const float4*)&X[(size_t)(m0 + row) * 256 + kn * 32 + cg * 4];
            }
#pragma unroll
            for (int i = 0; i < 4; ++i) {
                const int ch = i * 256 + t;
                const int row = ch >> 2, cg = ch & 3;
                wst[i] = *(const int4*)&W[(size_t)row * 256 + kn * 32 + cg * 8];
            }
        }

        const f16x8 af = *(const f16x8*)&Xs[(w * 16 + l16) * 40 + quad * 8];
        __builtin_amdgcn_s_setprio(1);
#pragma unroll
        for (int nt = 0; nt < 16; ++nt) {
            const f16x8 bf = *(const f16x8*)&Ws[(nt * 16 + l16) * 40 + quad * 8];
            acc[nt] = MFMA_F16(af, bf, acc[nt], 0, 0, 0);
        }
        __builtin_amdgcn_s_setprio(0);
        __syncthreads();   // all waves done reading Xs/Ws

        if (hasnext) {
#pragma unroll
            for (int i = 0; i < 2; ++i) {
                const int ch = i * 256 + t;
                const int row = ch >> 3, cg = ch & 7;
                *(ushort4*)&Xs[row * 40 + cg * 4] = f4_to_h4(xst[i]);
            }
#pragma unroll
            for (int i = 0; i < 4; ++i) {
                const int ch = i * 256 + t;
                const int row = ch >> 2, cg = ch & 3;
                *(int4*)&Ws[row * 40 + cg * 8] = wst[i];
            }
        }
        __syncthreads();   // writes visible; also makes smem safe for epilogue
    }

    if (z < 2) {
        u16* __restrict__ Y = (z == 0) ? Qh : Kh;
        // C-layout -> Ds[n][d] (scalar u16 stores, block-local)
#pragma unroll
        for (int nt = 0; nt < 16; ++nt) {
            const int col = nt * 16 + l16;
            const float bb = bias[col];
#pragma unroll
            for (int r = 0; r < 4; ++r)
                smem[(w * 16 + quad * 4 + r) * 264 + col] = f2h(acc[nt][r] + bb);
        }
        __syncthreads();
        // coalesced row-major stores: 64 rows x 32 int4 = 2048 chunks, 8/thread
#pragma unroll
        for (int i = 0; i < 8; ++i) {
            const int ch = i * 256 + t;
            const int row = ch >> 5, cg = ch & 31;
            *(int4*)&Y[(size_t)(m0 + row) * 256 + cg * 8] =
                *(const int4*)&smem[row * 264 + cg * 8];
        }
    } else {
        // C-layout -> Dt[d][n] (ushort4 over r), then coalesced Vt rows
        const int b  = m0 >> 11;
        const int n0 = m0 & 2047;
#pragma unroll
        for (int nt = 0; nt < 16; ++nt) {
            const int col = nt * 16 + l16;
            const float bb = bias[col];
            ushort4 h4;
            h4.x = f2h(acc[nt][0] + bb);
            h4.y = f2h(acc[nt][1] + bb);
            h4.z = f2h(acc[nt][2] + bb);
            h4.w = f2h(acc[nt][3] + bb);
            *(ushort4*)&smem[col * 72 + w * 16 + quad * 4] = h4;
        }
        __syncthreads();
        // 256 d-rows x 8 int4 chunks (64 n each) = 2048 chunks, 8/thread
#pragma unroll
        for (int i = 0; i < 8; ++i) {
            const int ch = i * 256 + t;
            const int row = ch >> 3, cg = ch & 7;
            *(int4*)&Vt[(size_t)b * 524288 + (size_t)row * 2048 + n0 + cg * 8] =
                *(const int4*)&smem[row * 72 + cg * 8];
        }
    }
}

// ---------------------------------------------------------------------------
// Kernel 2: flash attention, transposed scores. split-K x nz (nz=4).
// R15: latency pipeline. Occupancy is register-capped at 2 waves/SIMD
// (~184 combined VGPR+acc regs -> floor(512/184)=2), so raising the grid
// (R14) changed nothing. Instead hide the per-tile global-load latency
// INSIDE the wave: double-buffered K/V LDS (74.7KB, still 2 blocks/CU),
// next-tile loads issued before compute (T14 issue-early), ds_writes after
// compute (write-late), ONE barrier per tile (was two). +32 staged VGPRs is
// free headroom below the 256-reg cliff (launch_bounds(256,2) guards it).
// ---------------------------------------------------------------------------
__global__ __launch_bounds__(256, 2) void attn(
    const u16* __restrict__ Qh, const u16* __restrict__ Kg,
    const u16* __restrict__ Vt, u16* __restrict__ Op,
    u16* __restrict__ OutS, float* __restrict__ lmpL, float* __restrict__ lmpM)
{
    const int nz = gridDim.z;
    const int z  = blockIdx.z;
    const int tbase = 64 / nz, trem = 64 % nz;
    const int my_tiles = tbase + (z < trem ? 1 : 0);
    const int tile0    = tbase * z + (z < trem ? z : trem);

    const int b  = blockIdx.y;
    const int q0 = blockIdx.x * 64;
    const int t    = threadIdx.x;
    const int w    = t >> 6;
    const int lane = t & 63;
    const int quad = lane >> 4;
    const int l16  = lane & 15;

    __shared__ __align__(16) u16 smem[2 * 18688];   // 74752 B, dbuf
    u16* Os = smem;                // epilogue reuse: 64 x 264

    f16x8 qf[8];
    {
        const size_t qrow = (size_t)(b * 2048 + q0 + w * 16 + l16) * 256;
#pragma unroll
        for (int kc = 0; kc < 8; ++kc)
            qf[kc] = *(const f16x8*)&Qh[qrow + kc * 32 + quad * 8];
    }

    f32x4 O[16];
#pragma unroll
    for (int i = 0; i < 16; ++i) O[i] = f32x4{0.f, 0.f, 0.f, 0.f};
    float mrow = -1e30f, lrow = 0.f;

    int4 kst[4], vst[4];
    // prologue: stage tile0 -> regs -> buf0
    {
        const int kt = tile0 * 32;
#pragma unroll
        for (int i = 0; i < 4; ++i) {
            const int ch = i * 256 + t;
            const int row = ch >> 5, cg = ch & 31;
            const int prow = ((row >> 2) & 3) * 8 + (row >> 4) * 4 + (row & 3);
            kst[i] = *(const int4*)&Kg[(size_t)(b * 2048 + kt + prow) * 256 + cg * 8];
        }
#pragma unroll
        for (int i = 0; i < 4; ++i) {
            const int ch = i * 256 + t;
            const int row = ch >> 2, cg = ch & 3;
            vst[i] = *(const int4*)&Vt[(size_t)b * 524288 + (size_t)row * 2048 + kt + cg * 8];
        }
#pragma unroll
        for (int i = 0; i < 4; ++i) {
            const int ch = i * 256 + t;
            const int row = ch >> 5, cg = ch & 31;
            *(int4*)&smem[row * 264 + cg * 8] = kst[i];
        }
#pragma unroll
        for (int i = 0; i < 4; ++i) {
            const int ch = i * 256 + t;
            const int row = ch >> 2, cg = ch & 3;
            *(int4*)&smem[8448 + row * 40 + cg * 8] = vst[i];
        }
    }
    __syncthreads();

    for (int it = 0; it < my_tiles; ++it) {
        u16* __restrict__ Kc = smem + (it & 1) * 18688;
        u16* __restrict__ Vc = Kc + 8448;
        u16* __restrict__ Kn = smem + ((it & 1) ^ 1) * 18688;
        u16* __restrict__ Vn = Kn + 8448;
        const bool hasnext = (it + 1 < my_tiles);
        if (hasnext) {
            const int kt = (tile0 + it + 1) * 32;
#pragma unroll
            for (int i = 0; i < 4; ++i) {
                const int ch = i * 256 + t;
                const int row = ch >> 5, cg = ch & 31;
                const int prow = ((row >> 2) & 3) * 8 + (row >> 4) * 4 + (row & 3);
                kst[i] = *(const int4*)&Kg[(size_t)(b * 2048 + kt + prow) * 256 + cg * 8];
            }
#pragma unroll
            for (int i = 0; i < 4; ++i) {
                const int ch = i * 256 + t;
                const int row = ch >> 2, cg = ch & 3;
                vst[i] = *(const int4*)&Vt[(size_t)b * 524288 + (size_t)row * 2048 + kt + cg * 8];
            }
        }

        f32x4 S[2];
        S[0] = f32x4{0.f, 0.f, 0.f, 0.f};
        S[1] = f32x4{0.f, 0.f, 0.f, 0.f};
        __builtin_amdgcn_s_setprio(1);
#pragma unroll
        for (int kc = 0; kc < 8; ++kc) {
#pragma unroll
            for (int kn = 0; kn < 2; ++kn) {
                const f16x8 kf = *(const f16x8*)&Kc[(kn * 16 + l16) * 264 + kc * 32 + quad * 8];
                S[kn] = MFMA_F16(kf, qf[kc], S[kn], 0, 0, 0);
            }
        }
        __builtin_amdgcn_s_setprio(0);

        float mt = fmaxf(fmaxf(fmaxf(S[0][0], S[0][1]), fmaxf(S[0][2], S[0][3])),
                         fmaxf(fmaxf(S[1][0], S[1][1]), fmaxf(S[1][2], S[1][3])));
        mt = fmaxf(mt, __shfl_xor(mt, 16));
        mt = fmaxf(mt, __shfl_xor(mt, 32));
        // T13 defer-max: only rescale when the tile max grows past mrow+8.
        if (__any(mt - mrow > 8.f)) {
            const float mnew = fmaxf(mrow, mt);
            const float a = __expf(mrow - mnew);
            lrow *= a;
#pragma unroll
            for (int dv = 0; dv < 16; ++dv)
#pragma unroll
                for (int r = 0; r < 4; ++r) O[dv][r] *= a;
            mrow = mnew;
        }
        float p[2][4];
        float s = 0.f;
#pragma unroll
        for (int kn = 0; kn < 2; ++kn)
#pragma unroll
            for (int r = 0; r < 4; ++r) {
                p[kn][r] = __expf(S[kn][r] - mrow);
                s += p[kn][r];
            }
        s += __shfl_xor(s, 16);
        s += __shfl_xor(s, 32);
        lrow += s;

        f16x8 pfv;
#pragma unroll
        for (int kn = 0; kn < 2; ++kn)
#pragma unroll
            for (int r = 0; r < 4; ++r)
                pfv[kn * 4 + r] = (_Float16)p[kn][r];

        __builtin_amdgcn_s_setprio(1);
#pragma unroll
        for (int dvt = 0; dvt < 16; ++dvt) {
            const f16x8 vf = *(const f16x8*)&Vc[(dvt * 16 + l16) * 40 + quad * 8];
            O[dvt] = MFMA_F16(vf, pfv, O[dvt], 0, 0, 0);
        }
        __builtin_amdgcn_s_setprio(0);

        if (hasnext) {
            // write-late: vmcnt drain for kst/vst lands here, after compute
#pragma unroll
            for (int i = 0; i < 4; ++i) {
                const int ch = i * 256 + t;
                const int row = ch >> 5, cg = ch & 31;
                *(int4*)&Kn[row * 264 + cg * 8] = kst[i];
            }
#pragma unroll
            for (int i = 0; i < 4; ++i) {
                const int ch = i * 256 + t;
                const int row = ch >> 2, cg = ch & 3;
                *(int4*)&Vn[row * 40 + cg * 8] = vst[i];
            }
        }
        __syncthreads();   // single barrier per tile (dbuf makes this legal)
    }

    {
        const float rl = 1.0f / lrow;
#pragma unroll
        for (int dvt = 0; dvt < 16; ++dvt) {
            ushort4 h4;
            h4.x = f2h(O[dvt][0] * rl);
            h4.y = f2h(O[dvt][1] * rl);
            h4.z = f2h(O[dvt][2] * rl);
            h4.w = f2h(O[dvt][3] * rl);
            *(ushort4*)&Os[(w * 16 + l16) * 264 + dvt * 16 + quad * 4] = h4;
        }
        if (quad == 0) {
            const int grow = b * 2048 + q0 + w * 16 + l16;
            lmpL[z * 16384 + grow] = lrow;
            lmpM[z * 16384 + grow] = mrow;
        }
    }
    __syncthreads();

    {
        const int row = t >> 2;
        if (z < 2) {
            u16* __restrict__ Oz = Op + (size_t)z * 4194304;
#pragma unroll
            for (int i = 0; i < 8; ++i) {
                const int chunk = (t & 3) * 8 + i;
                *(int4*)&Oz[(size_t)(b * 2048 + q0 + row) * 256 + chunk * 8] =
                    *(const int4*)&Os[row * 264 + chunk * 8];
            }
        } else {
            // packed into d_out scratch: row m -> u16[m*512 + (z-2)*256 ...]
            u16* __restrict__ Oz = OutS + (size_t)(z - 2) * 256;
#pragma unroll
            for (int i = 0; i < 8; ++i) {
                const int chunk = (t & 3) * 8 + i;
                *(int4*)&Oz[(size_t)(b * 2048 + q0 + row) * 512 + chunk * 8] =
                    *(const int4*)&Os[row * 264 + chunk * 8];
            }
        }
    }
}

// ---------------------------------------------------------------------------
// Kernel 3: combine 4 partials + out projection + LayerNorm + LeakyReLU.
// R15: same T14 issue-early/write-late split on the k-loop.
// ---------------------------------------------------------------------------
__global__ __launch_bounds__(256) void outproj_ln(
    const u16* __restrict__ Op, const u16* __restrict__ OutS,
    const float* __restrict__ lmpL, const float* __restrict__ lmpM,
    const u16* __restrict__ Woh, const float* __restrict__ bo,
    const float* __restrict__ gamma, const float* __restrict__ beta,
    float* __restrict__ out)
{
    const int m0   = blockIdx.x * 64;
    const int t    = threadIdx.x;
    const int w    = t >> 6;
    const int lane = t & 63;
    const int quad = lane >> 4;
    const int l16  = lane & 15;

    __shared__ __align__(16) u16 Ls[64 * 40];
    __shared__ __align__(16) u16 Ws[256 * 40];
    __shared__ _Float16 wls[4][64];

    const int orow = t >> 2, ocg = t & 3;

    int4 ost[4], wst[4];
    // prologue: issue kc=0 loads (before wls barrier; latency overlaps it)
    {
        const size_t off  = (size_t)(m0 + orow) * 256 + ocg * 8;
        const size_t offS = (size_t)(m0 + orow) * 512 + ocg * 8;
        ost[0] = *(const int4*)&Op[off];
        ost[1] = *(const int4*)&Op[4194304 + off];
        ost[2] = *(const int4*)&OutS[offS];
        ost[3] = *(const int4*)&OutS[offS + 256];
    }
#pragma unroll
    for (int i = 0; i < 4; ++i) {
        const int ch = i * 256 + t;
        const int row = ch >> 2, cg = ch & 3;
        wst[i] = *(const int4*)&Woh[(size_t)row * 256 + cg * 8];
    }

    if (t < 64) {
        const float l0 = lmpL[m0 + t],         l1 = lmpL[16384 + m0 + t];
        const float l2 = lmpL[32768 + m0 + t], l3 = lmpL[49152 + m0 + t];
        const float m0v = lmpM[m0 + t],          m1v = lmpM[16384 + m0 + t];
        const float m2v = lmpM[32768 + m0 + t],  m3v = lmpM[49152 + m0 + t];
        const float mm = fmaxf(fmaxf(m0v, m1v), fmaxf(m2v, m3v));
        const float u0 = l0 * __expf(m0v - mm);
        const float u1 = l1 * __expf(m1v - mm);
        const float u2 = l2 * __expf(m2v - mm);
        const float u3 = l3 * __expf(m3v - mm);
        const float inv = 1.0f / (u0 + u1 + u2 + u3);
        wls[0][t] = (_Float16)(u0 * inv);
        wls[1][t] = (_Float16)(u1 * inv);
        wls[2][t] = (_Float16)(u2 * inv);
        wls[3][t] = (_Float16)(u3 * inv);
    }
    __syncthreads();   // wls visible

    // prologue write phase
    {
        const _Float16 w0 = wls[0][orow], w1 = wls[1][orow];
        const _Float16 w2 = wls[2][orow], w3 = wls[3][orow];
        const f16x8 o0 = __builtin_bit_cast(f16x8, ost[0]);
        const f16x8 o1 = __builtin_bit_cast(f16x8, ost[1]);
        const f16x8 o2 = __builtin_bit_cast(f16x8, ost[2]);
        const f16x8 o3 = __builtin_bit_cast(f16x8, ost[3]);
        f16x8 lw;
#pragma unroll
        for (int j = 0; j < 8; ++j)
            lw[j] = o0[j] * w0 + o1[j] * w1 + o2[j] * w2 + o3[j] * w3;
        *(int4*)&Ls[orow * 40 + ocg * 8] = __builtin_bit_cast(int4, lw);
    }
#pragma unroll
    for (int i = 0; i < 4; ++i) {
        const int ch = i * 256 + t;
        const int row = ch >> 2, cg = ch & 3;
        *(int4*)&Ws[row * 40 + cg * 8] = wst[i];
    }
    __syncthreads();

    f32x4 acc[16];
#pragma unroll
    for (int i = 0; i < 16; ++i) acc[i] = f32x4{0.f, 0.f, 0.f, 0.f};

    for (int kc = 0; kc < 8; ++kc) {
        const bool hasnext = (kc < 7);
        if (hasnext) {
            const int kn = kc + 1;
            const size_t off  = (size_t)(m0 + orow) * 256 + kn * 32 + ocg * 8;
            const size_t offS = (size_t)(m0 + orow) * 512 + kn * 32 + ocg * 8;
            ost[0] = *(const int4*)&Op[off];
            ost[1] = *(const int4*)&Op[4194304 + off];
            ost[2] = *(const int4*)&OutS[offS];
            ost[3] = *(const int4*)&OutS[offS + 256];
#pragma unroll
            for (int i = 0; i < 4; ++i) {
                const int ch = i * 256 + t;
                const int row = ch >> 2, cg = ch & 3;
                wst[i] = *(const int4*)&Woh[(size_t)row * 256 + kn * 32 + cg * 8];
            }
        }

        const f16x8 af = *(const f16x8*)&Ls[(w * 16 + l16) * 40 + quad * 8];
        __builtin_amdgcn_s_setprio(1);
#pragma unroll
        for (int nt = 0; nt < 16; ++nt) {
            const f16x8 bf = *(const f16x8*)&Ws[(nt * 16 + l16) * 40 + quad * 8];
            acc[nt] = MFMA_F16(af, bf, acc[nt], 0, 0, 0);
        }
        __builtin_amdgcn_s_setprio(0);
        __syncthreads();

        if (hasnext) {
            const _Float16 w0 = wls[0][orow], w1 = wls[1][orow];
            const _Float16 w2 = wls[2][orow], w3 = wls[3][orow];
            const f16x8 o0 = __builtin_bit_cast(f16x8, ost[0]);
            const f16x8 o1 = __builtin_bit_cast(f16x8, ost[1]);
            const f16x8 o2 = __builtin_bit_cast(f16x8, ost[2]);
            const f16x8 o3 = __builtin_bit_cast(f16x8, ost[3]);
            f16x8 lw;
#pragma unroll
            for (int j = 0; j < 8; ++j)
                lw[j] = o0[j] * w0 + o1[j] * w1 + o2[j] * w2 + o3[j] * w3;
            *(int4*)&Ls[orow * 40 + ocg * 8] = __builtin_bit_cast(int4, lw);
#pragma unroll
            for (int i = 0; i < 4; ++i) {
                const int ch = i * 256 + t;
                const int row = ch >> 2, cg = ch & 3;
                *(int4*)&Ws[row * 40 + cg * 8] = wst[i];
            }
        }
        __syncthreads();
    }

    float g[16], bt[16], bb[16];
#pragma unroll
    for (int nt = 0; nt < 16; ++nt) {
        const int col = nt * 16 + l16;
        bb[nt] = bo[col]; g[nt] = gamma[col]; bt[nt] = beta[col];
    }

#pragma unroll
    for (int r = 0; r < 4; ++r) {
        float h[16];
        float sh = 0.f, sh2 = 0.f;
#pragma unroll
        for (int nt = 0; nt < 16; ++nt) {
            h[nt] = acc[nt][r] + bb[nt];
            sh  += h[nt];
            sh2 += h[nt] * h[nt];
        }
        sh  += __shfl_xor(sh, 1);  sh  += __shfl_xor(sh, 2);
        sh  += __shfl_xor(sh, 4);  sh  += __shfl_xor(sh, 8);
        sh2 += __shfl_xor(sh2, 1); sh2 += __shfl_xor(sh2, 2);
        sh2 += __shfl_xor(sh2, 4); sh2 += __shfl_xor(sh2, 8);
        const float mu  = sh * (1.f / 256.f);
        const float var = fmaxf(sh2 * (1.f / 256.f) - mu * mu, 0.f);
        const float rs  = rsqrtf(var + 1e-5f);
        const size_t row = (size_t)(m0 + w * 16 + quad * 4 + r) * 256;
#pragma unroll
        for (int nt = 0; nt < 16; ++nt) {
            const float hn = (h[nt] - mu) * rs * g[nt] + bt[nt];
            out[row + nt * 16 + l16] = (hn >= 0.f) ? hn : 0.01f * hn;
        }
    }
}

// ---------------------------------------------------------------------------
extern "C" void kernel_launch(void* const* d_in, const int* in_sizes, int n_in,
                              void* d_out, int out_size, void* d_ws, size_t ws_size,
                              hipStream_t stream)
{
    const float* x  = (const float*)d_in[0];
    const float* Wq = (const float*)d_in[1];
    const float* bq = (const float*)d_in[2];
    const float* Wk = (const float*)d_in[3];
    const float* bk = (const float*)d_in[4];
    const float* Wv = (const float*)d_in[5];
    const float* bv = (const float*)d_in[6];
    const float* Wo = (const float*)d_in[7];
    const float* bo = (const float*)d_in[8];
    const float* gm = (const float*)d_in[9];
    const float* bt = (const float*)d_in[10];
    float* out = (float*)d_out;

    // ws layout (u16): [W4 262144][Qh 4.19M][Kh 4.19M][Vt 4.19M][Op 2x4.19M][lmpM]
    // -> identical total d_ws footprint to the 199µs baseline.
    // l-stats (l[4][16384] f32, 256KB) live in the dead Wq/Wk/Wv half of W4
    // (first 196608 u16 = 384KB, dead after proj_qkv; Woh at +196608 intact).
    // split-K partials z=2,3 live packed inside d_out (scratch until outproj).
    u16* W4 = (u16*)d_ws;
    u16* Qh = W4 + 262144;
    u16* Kh = Qh + 4194304;
    u16* Vt = Kh + 4194304;
    u16* Op = Vt + 4194304;
    float* lmpM = (float*)(Op + 2 * 4194304);  // m[4][16384] (old lmp slot)
    float* lmpL = (float*)W4;                  // l[4][16384] (dead W region)
    u16* Woh = W4 + 196608;
    u16* OutS = (u16*)d_out;

    prep_w     <<<64,             256, 0, stream>>>(Wq, Wk, Wv, Wo, W4);
    proj_qkv   <<<dim3(256, 3),   256, 0, stream>>>(x, W4, bq, bk, bv, Qh, Kh, Vt);
    attn       <<<dim3(32, 8, 4), 256, 0, stream>>>(Qh, Kh, Vt, Op, OutS, lmpL, lmpM);
    outproj_ln <<<256,            256, 0, stream>>>(Op, OutS, lmpL, lmpM, Woh, bo, gm, bt, out);
}

// Round 4
// 214.689 us; speedup vs baseline: 1.4279x; 1.4279x over previous
//
#include <hip/hip_runtime.h>

typedef unsigned short u16;
typedef __attribute__((ext_vector_type(8))) _Float16 f16x8;
typedef __attribute__((ext_vector_type(4))) float f32x4;

#define MFMA_F16 __builtin_amdgcn_mfma_f32_16x16x32_f16

static __device__ __forceinline__ u16 f2h(float f) {
    return __builtin_bit_cast(u16, (_Float16)f);
}
static __device__ __forceinline__ ushort4 f4_to_h4(const float4 v) {
    ushort4 r;
    r.x = f2h(v.x); r.y = f2h(v.y); r.z = f2h(v.z); r.w = f2h(v.w);
    return r;
}

// ---------------------------------------------------------------------------
// Kernel 0: prep_w — convert Wq/Wk/Wv/Wo (4 x 16384 float4) fp32 -> fp16.
// ---------------------------------------------------------------------------
__global__ __launch_bounds__(256) void prep_w(
    const float* __restrict__ wq, const float* __restrict__ wk,
    const float* __restrict__ wv, const float* __restrict__ wo,
    u16* __restrict__ w4)
{
    const int tid = blockIdx.x * 256 + threadIdx.x;   // 16384 threads
    for (int i = tid; i < 65536; i += 16384) {
        const float* src = (i < 16384) ? wq : (i < 32768) ? wk
                         : (i < 49152) ? wv : wo;
        ((ushort4*)w4)[i] = f4_to_h4(((const float4*)src)[i & 16383]);
    }
}

// ---------------------------------------------------------------------------
// Kernel 1: Q/K/V projection, fp16 MFMA (R14 version — R15's reg-staged
// pipeline SPILLED: VGPR 120->88 reported, WRITE_SIZE 33->394MB. Reverted.)
// ---------------------------------------------------------------------------
__global__ __launch_bounds__(256) void proj_qkv(
    const float* __restrict__ X, const u16* __restrict__ w4,
    const float* __restrict__ bq, const float* __restrict__ bk,
    const float* __restrict__ bv,
    u16* __restrict__ Qh, u16* __restrict__ Kh, u16* __restrict__ Vt)
{
    const int z = blockIdx.y;
    const u16* __restrict__ W     = w4 + z * 65536;
    const float* __restrict__ bias = (z == 0) ? bq : (z == 1) ? bk : bv;

    const int m0   = blockIdx.x * 64;          // global row (b*2048 + n0)
    const int t    = threadIdx.x;
    const int w    = t >> 6;
    const int lane = t & 63;
    const int quad = lane >> 4;
    const int l16  = lane & 15;

    __shared__ __align__(16) u16 smem[18432];  // 36864 B
    u16* Xs = smem;            // 64 x 40 during k-loop
    u16* Ws = smem + 2560;     // 256 x 40 during k-loop

    f32x4 acc[16];
#pragma unroll
    for (int i = 0; i < 16; ++i) acc[i] = f32x4{0.f, 0.f, 0.f, 0.f};

    for (int kc = 0; kc < 8; ++kc) {
        // X tile fp32 -> fp16: 64 rows x 8 float4-chunks = 512, 2/thread
#pragma unroll
        for (int i = 0; i < 2; ++i) {
            const int ch = i * 256 + t;
            const int row = ch >> 3, cg = ch & 7;
            const float4 v = *(const float4*)&X[(size_t)(m0 + row) * 256 + kc * 32 + cg * 4];
            *(ushort4*)&Xs[row * 40 + cg * 4] = f4_to_h4(v);
        }
        // W tile (fp16 pre-converted): 1024 int4-chunks, 4/thread
#pragma unroll
        for (int i = 0; i < 4; ++i) {
            const int ch = i * 256 + t;
            const int row = ch >> 2, cg = ch & 3;
            *(int4*)&Ws[row * 40 + cg * 8] =
                *(const int4*)&W[(size_t)row * 256 + kc * 32 + cg * 8];
        }
        __syncthreads();

        const f16x8 af = *(const f16x8*)&Xs[(w * 16 + l16) * 40 + quad * 8];
#pragma unroll
        for (int nt = 0; nt < 16; ++nt) {
            const f16x8 bf = *(const f16x8*)&Ws[(nt * 16 + l16) * 40 + quad * 8];
            acc[nt] = MFMA_F16(af, bf, acc[nt], 0, 0, 0);
        }
        __syncthreads();   // also makes smem safe to reuse in the epilogue
    }

    if (z < 2) {
        u16* __restrict__ Y = (z == 0) ? Qh : Kh;
        // C-layout -> Ds[n][d] (scalar u16 stores, block-local)
#pragma unroll
        for (int nt = 0; nt < 16; ++nt) {
            const int col = nt * 16 + l16;
            const float bb = bias[col];
#pragma unroll
            for (int r = 0; r < 4; ++r)
                smem[(w * 16 + quad * 4 + r) * 264 + col] = f2h(acc[nt][r] + bb);
        }
        __syncthreads();
        // coalesced row-major stores: 64 rows x 32 int4 = 2048 chunks, 8/thread
#pragma unroll
        for (int i = 0; i < 8; ++i) {
            const int ch = i * 256 + t;
            const int row = ch >> 5, cg = ch & 31;
            *(int4*)&Y[(size_t)(m0 + row) * 256 + cg * 8] =
                *(const int4*)&smem[row * 264 + cg * 8];
        }
    } else {
        // C-layout -> Dt[d][n] (ushort4 over r), then coalesced Vt rows
        const int b  = m0 >> 11;
        const int n0 = m0 & 2047;
#pragma unroll
        for (int nt = 0; nt < 16; ++nt) {
            const int col = nt * 16 + l16;
            const float bb = bias[col];
            ushort4 h4;
            h4.x = f2h(acc[nt][0] + bb);
            h4.y = f2h(acc[nt][1] + bb);
            h4.z = f2h(acc[nt][2] + bb);
            h4.w = f2h(acc[nt][3] + bb);
            *(ushort4*)&smem[col * 72 + w * 16 + quad * 4] = h4;
        }
        __syncthreads();
        // 256 d-rows x 8 int4 chunks (64 n each) = 2048 chunks, 8/thread
#pragma unroll
        for (int i = 0; i < 8; ++i) {
            const int ch = i * 256 + t;
            const int row = ch >> 3, cg = ch & 7;
            *(int4*)&Vt[(size_t)b * 524288 + (size_t)row * 2048 + n0 + cg * 8] =
                *(const int4*)&smem[row * 72 + cg * 8];
        }
    }
}

// ---------------------------------------------------------------------------
// Kernel 2: flash attention, transposed scores. split-K x nz (nz=2).
// R16: KVBLK 32 -> 64. attn is latency-bound (all pipes <25%) and occupancy
// is reg/LDS-capped at 2 blocks/CU; R15 showed adding staged registers
// spills. So amortize instead: 64-key tiles halve the barrier count, the
// shuffle reduction trees, the rescale checks, and the per-tile load-latency
// exposures, with the same total MFMA/exp work. K rows pre-permuted by
// prow64 = ((row>>2)&3)*8 + ((row>>4)&1)*4 + (row&3) + (row&32) (bijective)
// so P lands in-register in exact B-fragment order for the two PV half-K
// MFMAs (pf0: keys quad*8+j, pf1: keys 32+quad*8+j).
// LDS: Ks 64x264 + Vs 256x72 = 70656 B -> still 2 blocks/CU.
// defer-max (T13, THR=8) + setprio (T5) kept from the measured R14.
// ---------------------------------------------------------------------------
__global__ __launch_bounds__(256) void attn(
    const u16* __restrict__ Qh, const u16* __restrict__ Kg,
    const u16* __restrict__ Vt, u16* __restrict__ Op, float* __restrict__ lmp)
{
    const int nz = gridDim.z;          // 2
    const int z  = blockIdx.z;
    const int ntiles = 32 / nz;        // 64-key tiles: 32 total
    const int tile0  = ntiles * z;

    const int b  = blockIdx.y;
    const int q0 = blockIdx.x * 64;
    const int t    = threadIdx.x;
    const int w    = t >> 6;
    const int lane = t & 63;
    const int quad = lane >> 4;
    const int l16  = lane & 15;

    __shared__ __align__(16) u16 smem[35328];   // 70656 B
    u16* Ks = smem;                // 64 x 264
    u16* Vs = smem + 16896;        // 256 x 72
    u16* Os = smem;                // epilogue reuse: 64 x 264

    f16x8 qf[8];
    {
        const size_t qrow = (size_t)(b * 2048 + q0 + w * 16 + l16) * 256;
#pragma unroll
        for (int kc = 0; kc < 8; ++kc)
            qf[kc] = *(const f16x8*)&Qh[qrow + kc * 32 + quad * 8];
    }

    f32x4 O[16];
#pragma unroll
    for (int i = 0; i < 16; ++i) O[i] = f32x4{0.f, 0.f, 0.f, 0.f};
    float mrow = -1e30f, lrow = 0.f;

    for (int it = 0; it < ntiles; ++it) {
        const int kt = (tile0 + it) * 64;
        // K: 64 rows x 32 int4 chunks = 2048, 8/thread (prow64 permuted)
#pragma unroll
        for (int i = 0; i < 8; ++i) {
            const int ch = i * 256 + t;
            const int row = ch >> 5, cg = ch & 31;
            const int prow = ((row >> 2) & 3) * 8 + ((row >> 4) & 1) * 4
                           + (row & 3) + (row & 32);
            *(int4*)&Ks[row * 264 + cg * 8] =
                *(const int4*)&Kg[(size_t)(b * 2048 + kt + prow) * 256 + cg * 8];
        }
        // V: 256 d-rows x 8 int4 chunks (64 keys) = 2048, 8/thread
#pragma unroll
        for (int i = 0; i < 8; ++i) {
            const int ch = i * 256 + t;
            const int row = ch >> 3, cg = ch & 7;
            *(int4*)&Vs[row * 72 + cg * 8] =
                *(const int4*)&Vt[(size_t)b * 524288 + (size_t)row * 2048 + kt + cg * 8];
        }
        __syncthreads();

        f32x4 S[4];
#pragma unroll
        for (int kn = 0; kn < 4; ++kn) S[kn] = f32x4{0.f, 0.f, 0.f, 0.f};
        __builtin_amdgcn_s_setprio(1);
#pragma unroll
        for (int kc = 0; kc < 8; ++kc) {
#pragma unroll
            for (int kn = 0; kn < 4; ++kn) {
                const f16x8 kf = *(const f16x8*)&Ks[(kn * 16 + l16) * 264 + kc * 32 + quad * 8];
                S[kn] = MFMA_F16(kf, qf[kc], S[kn], 0, 0, 0);
            }
        }
        __builtin_amdgcn_s_setprio(0);

        float mt = -1e30f;
#pragma unroll
        for (int kn = 0; kn < 4; ++kn)
            mt = fmaxf(mt, fmaxf(fmaxf(S[kn][0], S[kn][1]), fmaxf(S[kn][2], S[kn][3])));
        mt = fmaxf(mt, __shfl_xor(mt, 16));
        mt = fmaxf(mt, __shfl_xor(mt, 32));
        // T13 defer-max: only rescale when the tile max grows past mrow+8.
        // P is then bounded by e^8 (~2981), inside f16 range; O/l stay
        // consistently relative to mrow -> final norm / split-K combine OK.
        if (__any(mt - mrow > 8.f)) {
            const float mnew = fmaxf(mrow, mt);
            const float a = __expf(mrow - mnew);
            lrow *= a;
#pragma unroll
            for (int dv = 0; dv < 16; ++dv)
#pragma unroll
                for (int r = 0; r < 4; ++r) O[dv][r] *= a;
            mrow = mnew;
        }
        float p[4][4];
        float s = 0.f;
#pragma unroll
        for (int kn = 0; kn < 4; ++kn)
#pragma unroll
            for (int r = 0; r < 4; ++r) {
                p[kn][r] = __expf(S[kn][r] - mrow);
                s += p[kn][r];
            }
        s += __shfl_xor(s, 16);
        s += __shfl_xor(s, 32);
        lrow += s;

        f16x8 pf0, pf1;
#pragma unroll
        for (int kn = 0; kn < 2; ++kn)
#pragma unroll
            for (int r = 0; r < 4; ++r) {
                pf0[kn * 4 + r] = (_Float16)p[kn][r];
                pf1[kn * 4 + r] = (_Float16)p[kn + 2][r];
            }

        __builtin_amdgcn_s_setprio(1);
#pragma unroll
        for (int dvt = 0; dvt < 16; ++dvt) {
            const f16x8 vf0 = *(const f16x8*)&Vs[(dvt * 16 + l16) * 72 + quad * 8];
            O[dvt] = MFMA_F16(vf0, pf0, O[dvt], 0, 0, 0);
            const f16x8 vf1 = *(const f16x8*)&Vs[(dvt * 16 + l16) * 72 + 32 + quad * 8];
            O[dvt] = MFMA_F16(vf1, pf1, O[dvt], 0, 0, 0);
        }
        __builtin_amdgcn_s_setprio(0);
        __syncthreads();
    }

    {
        const float rl = 1.0f / lrow;
#pragma unroll
        for (int dvt = 0; dvt < 16; ++dvt) {
            ushort4 h4;
            h4.x = f2h(O[dvt][0] * rl);
            h4.y = f2h(O[dvt][1] * rl);
            h4.z = f2h(O[dvt][2] * rl);
            h4.w = f2h(O[dvt][3] * rl);
            *(ushort4*)&Os[(w * 16 + l16) * 264 + dvt * 16 + quad * 4] = h4;
        }
        if (quad == 0) {
            const int grow = b * 2048 + q0 + w * 16 + l16;
            lmp[z * 16384 + grow]        = lrow;
            lmp[(nz + z) * 16384 + grow] = mrow;
        }
    }
    __syncthreads();

    u16* __restrict__ Oz = Op + (size_t)z * 4194304;
    {
        const int row = t >> 2;
#pragma unroll
        for (int i = 0; i < 8; ++i) {
            const int chunk = (t & 3) * 8 + i;
            *(int4*)&Oz[(size_t)(b * 2048 + q0 + row) * 256 + chunk * 8] =
                *(const int4*)&Os[row * 264 + chunk * 8];
        }
    }
}

// ---------------------------------------------------------------------------
// Kernel 3: combine 2 partials + out projection + LayerNorm + LeakyReLU.
// (R14/R0 version — R15's pipelined variant reverted with the spill.)
// ---------------------------------------------------------------------------
__global__ __launch_bounds__(256) void outproj_ln(
    const u16* __restrict__ Op, const float* __restrict__ lmp,
    const u16* __restrict__ Woh, const float* __restrict__ bo,
    const float* __restrict__ gamma, const float* __restrict__ beta,
    float* __restrict__ out)
{
    const int m0   = blockIdx.x * 64;
    const int t    = threadIdx.x;
    const int w    = t >> 6;
    const int lane = t & 63;
    const int quad = lane >> 4;
    const int l16  = lane & 15;

    __shared__ __align__(16) u16 Ls[64 * 40];
    __shared__ __align__(16) u16 Ws[256 * 40];
    __shared__ _Float16 w0s[64], w1s[64];

    if (t < 64) {
        const float l0 = lmp[m0 + t],          l1 = lmp[16384 + m0 + t];
        const float mm0 = lmp[32768 + m0 + t], mm1 = lmp[49152 + m0 + t];
        const float mm = fmaxf(mm0, mm1);
        const float u0 = l0 * __expf(mm0 - mm);
        const float u1 = l1 * __expf(mm1 - mm);
        const float inv = 1.0f / (u0 + u1);
        w0s[t] = (_Float16)(u0 * inv);
        w1s[t] = (_Float16)(u1 * inv);
    }
    __syncthreads();

    f32x4 acc[16];
#pragma unroll
    for (int i = 0; i < 16; ++i) acc[i] = f32x4{0.f, 0.f, 0.f, 0.f};

    for (int kc = 0; kc < 8; ++kc) {
        {
            const int row = t >> 2, cg = t & 3;
            const size_t off = (size_t)(m0 + row) * 256 + kc * 32 + cg * 8;
            const f16x8 o0 = __builtin_bit_cast(f16x8, *(const int4*)&Op[off]);
            const f16x8 o1 = __builtin_bit_cast(f16x8, *(const int4*)&Op[4194304 + off]);
            const _Float16 w0 = w0s[row], w1 = w1s[row];
            f16x8 lw;
#pragma unroll
            for (int j = 0; j < 8; ++j) lw[j] = o0[j] * w0 + o1[j] * w1;
            *(int4*)&Ls[row * 40 + cg * 8] = __builtin_bit_cast(int4, lw);
        }
#pragma unroll
        for (int i = 0; i < 4; ++i) {
            const int ch = i * 256 + t;
            const int row = ch >> 2, cg = ch & 3;
            *(int4*)&Ws[row * 40 + cg * 8] =
                *(const int4*)&Woh[(size_t)row * 256 + kc * 32 + cg * 8];
        }
        __syncthreads();

        const f16x8 af = *(const f16x8*)&Ls[(w * 16 + l16) * 40 + quad * 8];
#pragma unroll
        for (int nt = 0; nt < 16; ++nt) {
            const f16x8 bf = *(const f16x8*)&Ws[(nt * 16 + l16) * 40 + quad * 8];
            acc[nt] = MFMA_F16(af, bf, acc[nt], 0, 0, 0);
        }
        __syncthreads();
    }

    float g[16], bt[16], bb[16];
#pragma unroll
    for (int nt = 0; nt < 16; ++nt) {
        const int col = nt * 16 + l16;
        bb[nt] = bo[col]; g[nt] = gamma[col]; bt[nt] = beta[col];
    }

#pragma unroll
    for (int r = 0; r < 4; ++r) {
        float h[16];
        float sh = 0.f, sh2 = 0.f;
#pragma unroll
        for (int nt = 0; nt < 16; ++nt) {
            h[nt] = acc[nt][r] + bb[nt];
            sh  += h[nt];
            sh2 += h[nt] * h[nt];
        }
        sh  += __shfl_xor(sh, 1);  sh  += __shfl_xor(sh, 2);
        sh  += __shfl_xor(sh, 4);  sh  += __shfl_xor(sh, 8);
        sh2 += __shfl_xor(sh2, 1); sh2 += __shfl_xor(sh2, 2);
        sh2 += __shfl_xor(sh2, 4); sh2 += __shfl_xor(sh2, 8);
        const float mu  = sh * (1.f / 256.f);
        const float var = fmaxf(sh2 * (1.f / 256.f) - mu * mu, 0.f);
        const float rs  = rsqrtf(var + 1e-5f);
        const size_t row = (size_t)(m0 + w * 16 + quad * 4 + r) * 256;
#pragma unroll
        for (int nt = 0; nt < 16; ++nt) {
            const float hn = (h[nt] - mu) * rs * g[nt] + bt[nt];
            out[row + nt * 16 + l16] = (hn >= 0.f) ? hn : 0.01f * hn;
        }
    }
}

// ---------------------------------------------------------------------------
extern "C" void kernel_launch(void* const* d_in, const int* in_sizes, int n_in,
                              void* d_out, int out_size, void* d_ws, size_t ws_size,
                              hipStream_t stream)
{
    const float* x  = (const float*)d_in[0];
    const float* Wq = (const float*)d_in[1];
    const float* bq = (const float*)d_in[2];
    const float* Wk = (const float*)d_in[3];
    const float* bk = (const float*)d_in[4];
    const float* Wv = (const float*)d_in[5];
    const float* bv = (const float*)d_in[6];
    const float* Wo = (const float*)d_in[7];
    const float* bo = (const float*)d_in[8];
    const float* gm = (const float*)d_in[9];
    const float* bt = (const float*)d_in[10];
    float* out = (float*)d_out;

    // ws layout (u16): [W4 262144][Qh 4.19M][Kh 4.19M][Vt 4.19M][Op 2x4.19M][lmp]
    // (identical footprint to the 199µs baseline)
    u16* W4 = (u16*)d_ws;
    u16* Qh = W4 + 262144;
    u16* Kh = Qh + 4194304;
    u16* Vt = Kh + 4194304;
    u16* Op = Vt + 4194304;
    float* lmp = (float*)(Op + 2 * 4194304);  // l[2][16384], m[2][16384]
    u16* Woh = W4 + 196608;

    prep_w     <<<64,             256, 0, stream>>>(Wq, Wk, Wv, Wo, W4);
    proj_qkv   <<<dim3(256, 3),   256, 0, stream>>>(x, W4, bq, bk, bv, Qh, Kh, Vt);
    attn       <<<dim3(32, 8, 2), 256, 0, stream>>>(Qh, Kh, Vt, Op, lmp);
    outproj_ln <<<256,            256, 0, stream>>>(Op, lmp, Woh, bo, gm, bt, out);
}

// Round 5
// 181.187 us; speedup vs baseline: 1.6919x; 1.1849x over previous
//
#include <hip/hip_runtime.h>

typedef unsigned short u16;
typedef __attribute__((ext_vector_type(8))) _Float16 f16x8;
typedef __attribute__((ext_vector_type(4))) float f32x4;

#define MFMA_F16 __builtin_amdgcn_mfma_f32_16x16x32_f16

static __device__ __forceinline__ u16 f2h(float f) {
    return __builtin_bit_cast(u16, (_Float16)f);
}
static __device__ __forceinline__ ushort4 f4_to_h4(const float4 v) {
    ushort4 r;
    r.x = f2h(v.x); r.y = f2h(v.y); r.z = f2h(v.z); r.w = f2h(v.w);
    return r;
}

// ---------------------------------------------------------------------------
// Kernel 0: prep_w — convert Wq/Wk/Wv/Wo (4 x 16384 float4) fp32 -> fp16.
// ---------------------------------------------------------------------------
__global__ __launch_bounds__(256) void prep_w(
    const float* __restrict__ wq, const float* __restrict__ wk,
    const float* __restrict__ wv, const float* __restrict__ wo,
    u16* __restrict__ w4)
{
    const int tid = blockIdx.x * 256 + threadIdx.x;   // 16384 threads
    for (int i = tid; i < 65536; i += 16384) {
        const float* src = (i < 16384) ? wq : (i < 32768) ? wk
                         : (i < 49152) ? wv : wo;
        ((ushort4*)w4)[i] = f4_to_h4(((const float4*)src)[i & 16383]);
    }
}

// ---------------------------------------------------------------------------
// Kernel 1: Q/K/V projection, fp16 MFMA (measured-good R14 version).
// ---------------------------------------------------------------------------
__global__ __launch_bounds__(256) void proj_qkv(
    const float* __restrict__ X, const u16* __restrict__ w4,
    const float* __restrict__ bq, const float* __restrict__ bk,
    const float* __restrict__ bv,
    u16* __restrict__ Qh, u16* __restrict__ Kh, u16* __restrict__ Vt)
{
    const int z = blockIdx.y;
    const u16* __restrict__ W     = w4 + z * 65536;
    const float* __restrict__ bias = (z == 0) ? bq : (z == 1) ? bk : bv;

    const int m0   = blockIdx.x * 64;          // global row (b*2048 + n0)
    const int t    = threadIdx.x;
    const int w    = t >> 6;
    const int lane = t & 63;
    const int quad = lane >> 4;
    const int l16  = lane & 15;

    __shared__ __align__(16) u16 smem[18432];  // 36864 B
    u16* Xs = smem;            // 64 x 40 during k-loop
    u16* Ws = smem + 2560;     // 256 x 40 during k-loop

    f32x4 acc[16];
#pragma unroll
    for (int i = 0; i < 16; ++i) acc[i] = f32x4{0.f, 0.f, 0.f, 0.f};

    for (int kc = 0; kc < 8; ++kc) {
        // X tile fp32 -> fp16: 64 rows x 8 float4-chunks = 512, 2/thread
#pragma unroll
        for (int i = 0; i < 2; ++i) {
            const int ch = i * 256 + t;
            const int row = ch >> 3, cg = ch & 7;
            const float4 v = *(const float4*)&X[(size_t)(m0 + row) * 256 + kc * 32 + cg * 4];
            *(ushort4*)&Xs[row * 40 + cg * 4] = f4_to_h4(v);
        }
        // W tile (fp16 pre-converted): 1024 int4-chunks, 4/thread
#pragma unroll
        for (int i = 0; i < 4; ++i) {
            const int ch = i * 256 + t;
            const int row = ch >> 2, cg = ch & 3;
            *(int4*)&Ws[row * 40 + cg * 8] =
                *(const int4*)&W[(size_t)row * 256 + kc * 32 + cg * 8];
        }
        __syncthreads();

        const f16x8 af = *(const f16x8*)&Xs[(w * 16 + l16) * 40 + quad * 8];
#pragma unroll
        for (int nt = 0; nt < 16; ++nt) {
            const f16x8 bf = *(const f16x8*)&Ws[(nt * 16 + l16) * 40 + quad * 8];
            acc[nt] = MFMA_F16(af, bf, acc[nt], 0, 0, 0);
        }
        __syncthreads();   // also makes smem safe to reuse in the epilogue
    }

    if (z < 2) {
        u16* __restrict__ Y = (z == 0) ? Qh : Kh;
        // C-layout -> Ds[n][d] (scalar u16 stores, block-local)
#pragma unroll
        for (int nt = 0; nt < 16; ++nt) {
            const int col = nt * 16 + l16;
            const float bb = bias[col];
#pragma unroll
            for (int r = 0; r < 4; ++r)
                smem[(w * 16 + quad * 4 + r) * 264 + col] = f2h(acc[nt][r] + bb);
        }
        __syncthreads();
        // coalesced row-major stores: 64 rows x 32 int4 = 2048 chunks, 8/thread
#pragma unroll
        for (int i = 0; i < 8; ++i) {
            const int ch = i * 256 + t;
            const int row = ch >> 5, cg = ch & 31;
            *(int4*)&Y[(size_t)(m0 + row) * 256 + cg * 8] =
                *(const int4*)&smem[row * 264 + cg * 8];
        }
    } else {
        // C-layout -> Dt[d][n] (ushort4 over r), then coalesced Vt rows
        const int b  = m0 >> 11;
        const int n0 = m0 & 2047;
#pragma unroll
        for (int nt = 0; nt < 16; ++nt) {
            const int col = nt * 16 + l16;
            const float bb = bias[col];
            ushort4 h4;
            h4.x = f2h(acc[nt][0] + bb);
            h4.y = f2h(acc[nt][1] + bb);
            h4.z = f2h(acc[nt][2] + bb);
            h4.w = f2h(acc[nt][3] + bb);
            *(ushort4*)&smem[col * 72 + w * 16 + quad * 4] = h4;
        }
        __syncthreads();
        // 256 d-rows x 8 int4 chunks (64 n each) = 2048 chunks, 8/thread
#pragma unroll
        for (int i = 0; i < 8; ++i) {
            const int ch = i * 256 + t;
            const int row = ch >> 3, cg = ch & 7;
            *(int4*)&Vt[(size_t)b * 524288 + (size_t)row * 2048 + n0 + cg * 8] =
                *(const int4*)&smem[row * 72 + cg * 8];
        }
    }
}

// ---------------------------------------------------------------------------
// Kernel 2: flash attention, transposed scores. split-K x nz (nz=3).
// R17: register-cap attack. Four rounds establish: 2 blocks/CU because
// total unified regs (~112 arch + ~68 acc ~ 180) -> 2 waves/SIMD. Grid size
// (R14), reg-staged pipelining (R15: spill), KVBLK=64 (R16: occupancy halved)
// all failed to move that. This round: KVBLK=32 / 37.4KB LDS structure
// (3 blocks x 37.4KB = 112KB fits even a 128KB pool), launch_bounds(256,3)
// to force total <= ~170 regs, p[] float array fused away (exp->sum->f16 in
// one pass, ~8 regs), nz=3 -> 768 blocks = exactly 3/CU to fill the slot.
// Partial plumbing = R2's passing version (z=2 -> d_out scratch; l-stats in
// dead W region, m-stats in old lmp slot).
// Spill tripwire: WRITE_SIZE should stay ~25MB; R15's spill was 394MB.
// ---------------------------------------------------------------------------
__global__ __launch_bounds__(256, 3) void attn(
    const u16* __restrict__ Qh, const u16* __restrict__ Kg,
    const u16* __restrict__ Vt, u16* __restrict__ Op,
    u16* __restrict__ OutS, float* __restrict__ lmpL, float* __restrict__ lmpM)
{
    const int nz = gridDim.z;
    const int z  = blockIdx.z;
    const int tbase = 64 / nz, trem = 64 % nz;
    const int my_tiles = tbase + (z < trem ? 1 : 0);
    const int tile0    = tbase * z + (z < trem ? z : trem);

    const int b  = blockIdx.y;
    const int q0 = blockIdx.x * 64;
    const int t    = threadIdx.x;
    const int w    = t >> 6;
    const int lane = t & 63;
    const int quad = lane >> 4;
    const int l16  = lane & 15;

    __shared__ __align__(16) u16 smem[18688];   // 37376 B
    u16* Ks = smem;                // 32 x 264
    u16* Vs = smem + 8448;         // 256 x 40
    u16* Os = smem;                // epilogue reuse: 64 x 264

    f16x8 qf[8];
    {
        const size_t qrow = (size_t)(b * 2048 + q0 + w * 16 + l16) * 256;
#pragma unroll
        for (int kc = 0; kc < 8; ++kc)
            qf[kc] = *(const f16x8*)&Qh[qrow + kc * 32 + quad * 8];
    }

    f32x4 O[16];
#pragma unroll
    for (int i = 0; i < 16; ++i) O[i] = f32x4{0.f, 0.f, 0.f, 0.f};
    float mrow = -1e30f, lrow = 0.f;

    for (int it = 0; it < my_tiles; ++it) {
        const int kt = (tile0 + it) * 32;
#pragma unroll
        for (int i = 0; i < 4; ++i) {
            const int ch = i * 256 + t;
            const int row = ch >> 5, cg = ch & 31;
            const int prow = ((row >> 2) & 3) * 8 + (row >> 4) * 4 + (row & 3);
            *(int4*)&Ks[row * 264 + cg * 8] =
                *(const int4*)&Kg[(size_t)(b * 2048 + kt + prow) * 256 + cg * 8];
        }
#pragma unroll
        for (int i = 0; i < 4; ++i) {
            const int ch = i * 256 + t;
            const int row = ch >> 2, cg = ch & 3;
            *(int4*)&Vs[row * 40 + cg * 8] =
                *(const int4*)&Vt[(size_t)b * 524288 + (size_t)row * 2048 + kt + cg * 8];
        }
        __syncthreads();

        f32x4 S[2];
        S[0] = f32x4{0.f, 0.f, 0.f, 0.f};
        S[1] = f32x4{0.f, 0.f, 0.f, 0.f};
        __builtin_amdgcn_s_setprio(1);
#pragma unroll
        for (int kc = 0; kc < 8; ++kc) {
#pragma unroll
            for (int kn = 0; kn < 2; ++kn) {
                const f16x8 kf = *(const f16x8*)&Ks[(kn * 16 + l16) * 264 + kc * 32 + quad * 8];
                S[kn] = MFMA_F16(kf, qf[kc], S[kn], 0, 0, 0);
            }
        }
        __builtin_amdgcn_s_setprio(0);

        float mt = fmaxf(fmaxf(fmaxf(S[0][0], S[0][1]), fmaxf(S[0][2], S[0][3])),
                         fmaxf(fmaxf(S[1][0], S[1][1]), fmaxf(S[1][2], S[1][3])));
        mt = fmaxf(mt, __shfl_xor(mt, 16));
        mt = fmaxf(mt, __shfl_xor(mt, 32));
        // T13 defer-max: only rescale when the tile max grows past mrow+8.
        // P is then bounded by e^8 (~2981), inside f16 range; O/l stay
        // consistently relative to mrow -> final norm / split-K combine OK.
        if (__any(mt - mrow > 8.f)) {
            const float mnew = fmaxf(mrow, mt);
            const float a = __expf(mrow - mnew);
            lrow *= a;
#pragma unroll
            for (int dv = 0; dv < 16; ++dv)
#pragma unroll
                for (int r = 0; r < 4; ++r) O[dv][r] *= a;
            mrow = mnew;
        }
        // fused exp -> sum -> f16 convert (no float p[][] array)
        f16x8 pfv;
        float s = 0.f;
#pragma unroll
        for (int kn = 0; kn < 2; ++kn)
#pragma unroll
            for (int r = 0; r < 4; ++r) {
                const float e = __expf(S[kn][r] - mrow);
                s += e;
                pfv[kn * 4 + r] = (_Float16)e;
            }
        s += __shfl_xor(s, 16);
        s += __shfl_xor(s, 32);
        lrow += s;

        __builtin_amdgcn_s_setprio(1);
#pragma unroll
        for (int dvt = 0; dvt < 16; ++dvt) {
            const f16x8 vf = *(const f16x8*)&Vs[(dvt * 16 + l16) * 40 + quad * 8];
            O[dvt] = MFMA_F16(vf, pfv, O[dvt], 0, 0, 0);
        }
        __builtin_amdgcn_s_setprio(0);
        __syncthreads();
    }

    {
        const float rl = 1.0f / lrow;
#pragma unroll
        for (int dvt = 0; dvt < 16; ++dvt) {
            ushort4 h4;
            h4.x = f2h(O[dvt][0] * rl);
            h4.y = f2h(O[dvt][1] * rl);
            h4.z = f2h(O[dvt][2] * rl);
            h4.w = f2h(O[dvt][3] * rl);
            *(ushort4*)&Os[(w * 16 + l16) * 264 + dvt * 16 + quad * 4] = h4;
        }
        if (quad == 0) {
            const int grow = b * 2048 + q0 + w * 16 + l16;
            lmpL[z * 16384 + grow] = lrow;
            lmpM[z * 16384 + grow] = mrow;
        }
    }
    __syncthreads();

    {
        const int row = t >> 2;
        if (z < 2) {
            u16* __restrict__ Oz = Op + (size_t)z * 4194304;
#pragma unroll
            for (int i = 0; i < 8; ++i) {
                const int chunk = (t & 3) * 8 + i;
                *(int4*)&Oz[(size_t)(b * 2048 + q0 + row) * 256 + chunk * 8] =
                    *(const int4*)&Os[row * 264 + chunk * 8];
            }
        } else {
            // z==2 packed into d_out scratch: row m -> u16[m*512 + 0..255]
            u16* __restrict__ Oz = OutS;
#pragma unroll
            for (int i = 0; i < 8; ++i) {
                const int chunk = (t & 3) * 8 + i;
                *(int4*)&Oz[(size_t)(b * 2048 + q0 + row) * 512 + chunk * 8] =
                    *(const int4*)&Os[row * 264 + chunk * 8];
            }
        }
    }
}

// ---------------------------------------------------------------------------
// Kernel 3: combine 3 partials + out projection + LayerNorm + LeakyReLU.
// Partials 0,1 from Op workspace; 2 packed in d_out scratch (read fully for
// rows m0..m0+63 in the k-loop before the epilogue overwrites exactly those
// rows with f32 output -> no intra- or inter-block hazard; proven in R2).
// ---------------------------------------------------------------------------
__global__ __launch_bounds__(256) void outproj_ln(
    const u16* __restrict__ Op, const u16* __restrict__ OutS,
    const float* __restrict__ lmpL, const float* __restrict__ lmpM,
    const u16* __restrict__ Woh, const float* __restrict__ bo,
    const float* __restrict__ gamma, const float* __restrict__ beta,
    float* __restrict__ out)
{
    const int m0   = blockIdx.x * 64;
    const int t    = threadIdx.x;
    const int w    = t >> 6;
    const int lane = t & 63;
    const int quad = lane >> 4;
    const int l16  = lane & 15;

    __shared__ __align__(16) u16 Ls[64 * 40];
    __shared__ __align__(16) u16 Ws[256 * 40];
    __shared__ _Float16 wls[3][64];

    if (t < 64) {
        const float l0 = lmpL[m0 + t];
        const float l1 = lmpL[16384 + m0 + t];
        const float l2 = lmpL[32768 + m0 + t];
        const float m0v = lmpM[m0 + t];
        const float m1v = lmpM[16384 + m0 + t];
        const float m2v = lmpM[32768 + m0 + t];
        const float mm = fmaxf(fmaxf(m0v, m1v), m2v);
        const float u0 = l0 * __expf(m0v - mm);
        const float u1 = l1 * __expf(m1v - mm);
        const float u2 = l2 * __expf(m2v - mm);
        const float inv = 1.0f / (u0 + u1 + u2);
        wls[0][t] = (_Float16)(u0 * inv);
        wls[1][t] = (_Float16)(u1 * inv);
        wls[2][t] = (_Float16)(u2 * inv);
    }
    __syncthreads();

    f32x4 acc[16];
#pragma unroll
    for (int i = 0; i < 16; ++i) acc[i] = f32x4{0.f, 0.f, 0.f, 0.f};

    for (int kc = 0; kc < 8; ++kc) {
        {
            const int row = t >> 2, cg = t & 3;
            const size_t off  = (size_t)(m0 + row) * 256 + kc * 32 + cg * 8;
            const size_t offS = (size_t)(m0 + row) * 512 + kc * 32 + cg * 8;
            const f16x8 o0 = __builtin_bit_cast(f16x8, *(const int4*)&Op[off]);
            const f16x8 o1 = __builtin_bit_cast(f16x8, *(const int4*)&Op[4194304 + off]);
            const f16x8 o2 = __builtin_bit_cast(f16x8, *(const int4*)&OutS[offS]);
            const _Float16 w0 = wls[0][row], w1 = wls[1][row], w2 = wls[2][row];
            f16x8 lw;
#pragma unroll
            for (int j = 0; j < 8; ++j)
                lw[j] = o0[j] * w0 + o1[j] * w1 + o2[j] * w2;
            *(int4*)&Ls[row * 40 + cg * 8] = __builtin_bit_cast(int4, lw);
        }
#pragma unroll
        for (int i = 0; i < 4; ++i) {
            const int ch = i * 256 + t;
            const int row = ch >> 2, cg = ch & 3;
            *(int4*)&Ws[row * 40 + cg * 8] =
                *(const int4*)&Woh[(size_t)row * 256 + kc * 32 + cg * 8];
        }
        __syncthreads();

        const f16x8 af = *(const f16x8*)&Ls[(w * 16 + l16) * 40 + quad * 8];
#pragma unroll
        for (int nt = 0; nt < 16; ++nt) {
            const f16x8 bf = *(const f16x8*)&Ws[(nt * 16 + l16) * 40 + quad * 8];
            acc[nt] = MFMA_F16(af, bf, acc[nt], 0, 0, 0);
        }
        __syncthreads();
    }

    float g[16], bt[16], bb[16];
#pragma unroll
    for (int nt = 0; nt < 16; ++nt) {
        const int col = nt * 16 + l16;
        bb[nt] = bo[col]; g[nt] = gamma[col]; bt[nt] = beta[col];
    }

#pragma unroll
    for (int r = 0; r < 4; ++r) {
        float h[16];
        float sh = 0.f, sh2 = 0.f;
#pragma unroll
        for (int nt = 0; nt < 16; ++nt) {
            h[nt] = acc[nt][r] + bb[nt];
            sh  += h[nt];
            sh2 += h[nt] * h[nt];
        }
        sh  += __shfl_xor(sh, 1);  sh  += __shfl_xor(sh, 2);
        sh  += __shfl_xor(sh, 4);  sh  += __shfl_xor(sh, 8);
        sh2 += __shfl_xor(sh2, 1); sh2 += __shfl_xor(sh2, 2);
        sh2 += __shfl_xor(sh2, 4); sh2 += __shfl_xor(sh2, 8);
        const float mu  = sh * (1.f / 256.f);
        const float var = fmaxf(sh2 * (1.f / 256.f) - mu * mu, 0.f);
        const float rs  = rsqrtf(var + 1e-5f);
        const size_t row = (size_t)(m0 + w * 16 + quad * 4 + r) * 256;
#pragma unroll
        for (int nt = 0; nt < 16; ++nt) {
            const float hn = (h[nt] - mu) * rs * g[nt] + bt[nt];
            out[row + nt * 16 + l16] = (hn >= 0.f) ? hn : 0.01f * hn;
        }
    }
}

// ---------------------------------------------------------------------------
extern "C" void kernel_launch(void* const* d_in, const int* in_sizes, int n_in,
                              void* d_out, int out_size, void* d_ws, size_t ws_size,
                              hipStream_t stream)
{
    const float* x  = (const float*)d_in[0];
    const float* Wq = (const float*)d_in[1];
    const float* bq = (const float*)d_in[2];
    const float* Wk = (const float*)d_in[3];
    const float* bk = (const float*)d_in[4];
    const float* Wv = (const float*)d_in[5];
    const float* bv = (const float*)d_in[6];
    const float* Wo = (const float*)d_in[7];
    const float* bo = (const float*)d_in[8];
    const float* gm = (const float*)d_in[9];
    const float* bt = (const float*)d_in[10];
    float* out = (float*)d_out;

    // ws layout (u16): [W4 262144][Qh 4.19M][Kh 4.19M][Vt 4.19M][Op 2x4.19M][lmpM]
    // -> identical total d_ws footprint to the 199µs baseline.
    // l-stats (l[3][16384] f32) live in the dead Wq/Wk/Wv half of W4
    // (first 196608 u16 = 384KB, dead after proj_qkv; Woh at +196608 intact).
    // split-K partial z=2 lives packed inside d_out (scratch until outproj).
    u16* W4 = (u16*)d_ws;
    u16* Qh = W4 + 262144;
    u16* Kh = Qh + 4194304;
    u16* Vt = Kh + 4194304;
    u16* Op = Vt + 4194304;
    float* lmpM = (float*)(Op + 2 * 4194304);  // m[3][16384] (old lmp slot)
    float* lmpL = (float*)W4;                  // l[3][16384] (dead W region)
    u16* Woh = W4 + 196608;
    u16* OutS = (u16*)d_out;

    prep_w     <<<64,             256, 0, stream>>>(Wq, Wk, Wv, Wo, W4);
    proj_qkv   <<<dim3(256, 3),   256, 0, stream>>>(x, W4, bq, bk, bv, Qh, Kh, Vt);
    attn       <<<dim3(32, 8, 3), 256, 0, stream>>>(Qh, Kh, Vt, Op, OutS, lmpL, lmpM);
    outproj_ln <<<256,            256, 0, stream>>>(Op, OutS, lmpL, lmpM, Woh, bo, gm, bt, out);
}

// Round 6
// 177.428 us; speedup vs baseline: 1.7278x; 1.0212x over previous
//
#include <hip/hip_runtime.h>

typedef unsigned short u16;
typedef __attribute__((ext_vector_type(8))) _Float16 f16x8;
typedef __attribute__((ext_vector_type(4))) float f32x4;

#define MFMA_F16 __builtin_amdgcn_mfma_f32_16x16x32_f16

static __device__ __forceinline__ u16 f2h(float f) {
    return __builtin_bit_cast(u16, (_Float16)f);
}
static __device__ __forceinline__ ushort4 f4_to_h4(const float4 v) {
    ushort4 r;
    r.x = f2h(v.x); r.y = f2h(v.y); r.z = f2h(v.z); r.w = f2h(v.w);
    return r;
}

// ---------------------------------------------------------------------------
// Kernel 0: prep_w — convert Wq/Wk/Wv/Wo (4 x 16384 float4) fp32 -> fp16.
// ---------------------------------------------------------------------------
__global__ __launch_bounds__(256) void prep_w(
    const float* __restrict__ wq, const float* __restrict__ wk,
    const float* __restrict__ wv, const float* __restrict__ wo,
    u16* __restrict__ w4)
{
    const int tid = blockIdx.x * 256 + threadIdx.x;   // 16384 threads
    for (int i = tid; i < 65536; i += 16384) {
        const float* src = (i < 16384) ? wq : (i < 32768) ? wk
                         : (i < 49152) ? wv : wo;
        ((ushort4*)w4)[i] = f4_to_h4(((const float4*)src)[i & 16383]);
    }
}

// ---------------------------------------------------------------------------
// Kernel 1: Q/K/V projection, fp16 MFMA.
// R18: launch_bounds(256,3) — the R17 register-cap fix applied here. Same
// ~112+64-acc profile attn had pre-R17 (2 blocks/CU); forcing <=170 total
// regs lets the 768-block grid reach 3 blocks/CU. LDS 3x36.9KB=110.6KB ok.
// ---------------------------------------------------------------------------
__global__ __launch_bounds__(256, 3) void proj_qkv(
    const float* __restrict__ X, const u16* __restrict__ w4,
    const float* __restrict__ bq, const float* __restrict__ bk,
    const float* __restrict__ bv,
    u16* __restrict__ Qh, u16* __restrict__ Kh, u16* __restrict__ Vt)
{
    const int z = blockIdx.y;
    const u16* __restrict__ W     = w4 + z * 65536;
    const float* __restrict__ bias = (z == 0) ? bq : (z == 1) ? bk : bv;

    const int m0   = blockIdx.x * 64;          // global row (b*2048 + n0)
    const int t    = threadIdx.x;
    const int w    = t >> 6;
    const int lane = t & 63;
    const int quad = lane >> 4;
    const int l16  = lane & 15;

    __shared__ __align__(16) u16 smem[18432];  // 36864 B
    u16* Xs = smem;            // 64 x 40 during k-loop
    u16* Ws = smem + 2560;     // 256 x 40 during k-loop

    f32x4 acc[16];
#pragma unroll
    for (int i = 0; i < 16; ++i) acc[i] = f32x4{0.f, 0.f, 0.f, 0.f};

    for (int kc = 0; kc < 8; ++kc) {
        // X tile fp32 -> fp16: 64 rows x 8 float4-chunks = 512, 2/thread
#pragma unroll
        for (int i = 0; i < 2; ++i) {
            const int ch = i * 256 + t;
            const int row = ch >> 3, cg = ch & 7;
            const float4 v = *(const float4*)&X[(size_t)(m0 + row) * 256 + kc * 32 + cg * 4];
            *(ushort4*)&Xs[row * 40 + cg * 4] = f4_to_h4(v);
        }
        // W tile (fp16 pre-converted): 1024 int4-chunks, 4/thread
#pragma unroll
        for (int i = 0; i < 4; ++i) {
            const int ch = i * 256 + t;
            const int row = ch >> 2, cg = ch & 3;
            *(int4*)&Ws[row * 40 + cg * 8] =
                *(const int4*)&W[(size_t)row * 256 + kc * 32 + cg * 8];
        }
        __syncthreads();

        const f16x8 af = *(const f16x8*)&Xs[(w * 16 + l16) * 40 + quad * 8];
#pragma unroll
        for (int nt = 0; nt < 16; ++nt) {
            const f16x8 bf = *(const f16x8*)&Ws[(nt * 16 + l16) * 40 + quad * 8];
            acc[nt] = MFMA_F16(af, bf, acc[nt], 0, 0, 0);
        }
        __syncthreads();   // also makes smem safe to reuse in the epilogue
    }

    if (z < 2) {
        u16* __restrict__ Y = (z == 0) ? Qh : Kh;
        // C-layout -> Ds[n][d] (scalar u16 stores, block-local)
#pragma unroll
        for (int nt = 0; nt < 16; ++nt) {
            const int col = nt * 16 + l16;
            const float bb = bias[col];
#pragma unroll
            for (int r = 0; r < 4; ++r)
                smem[(w * 16 + quad * 4 + r) * 264 + col] = f2h(acc[nt][r] + bb);
        }
        __syncthreads();
        // coalesced row-major stores: 64 rows x 32 int4 = 2048 chunks, 8/thread
#pragma unroll
        for (int i = 0; i < 8; ++i) {
            const int ch = i * 256 + t;
            const int row = ch >> 5, cg = ch & 31;
            *(int4*)&Y[(size_t)(m0 + row) * 256 + cg * 8] =
                *(const int4*)&smem[row * 264 + cg * 8];
        }
    } else {
        // C-layout -> Dt[d][n] (ushort4 over r), then coalesced Vt rows
        const int b  = m0 >> 11;
        const int n0 = m0 & 2047;
#pragma unroll
        for (int nt = 0; nt < 16; ++nt) {
            const int col = nt * 16 + l16;
            const float bb = bias[col];
            ushort4 h4;
            h4.x = f2h(acc[nt][0] + bb);
            h4.y = f2h(acc[nt][1] + bb);
            h4.z = f2h(acc[nt][2] + bb);
            h4.w = f2h(acc[nt][3] + bb);
            *(ushort4*)&smem[col * 72 + w * 16 + quad * 4] = h4;
        }
        __syncthreads();
        // 256 d-rows x 8 int4 chunks (64 n each) = 2048 chunks, 8/thread
#pragma unroll
        for (int i = 0; i < 8; ++i) {
            const int ch = i * 256 + t;
            const int row = ch >> 3, cg = ch & 7;
            *(int4*)&Vt[(size_t)b * 524288 + (size_t)row * 2048 + n0 + cg * 8] =
                *(const int4*)&smem[row * 72 + cg * 8];
        }
    }
}

// ---------------------------------------------------------------------------
// Kernel 2: flash attention (R17, measured 71.3µs — UNCHANGED).
// split-K x nz (nz=3), KVBLK=32, launch_bounds(256,3), fused exp->sum->f16,
// defer-max (T13), setprio (T5). VGPR 84, occupancy ~27%, no spill.
// ---------------------------------------------------------------------------
__global__ __launch_bounds__(256, 3) void attn(
    const u16* __restrict__ Qh, const u16* __restrict__ Kg,
    const u16* __restrict__ Vt, u16* __restrict__ Op,
    u16* __restrict__ OutS, float* __restrict__ lmpL, float* __restrict__ lmpM)
{
    const int nz = gridDim.z;
    const int z  = blockIdx.z;
    const int tbase = 64 / nz, trem = 64 % nz;
    const int my_tiles = tbase + (z < trem ? 1 : 0);
    const int tile0    = tbase * z + (z < trem ? z : trem);

    const int b  = blockIdx.y;
    const int q0 = blockIdx.x * 64;
    const int t    = threadIdx.x;
    const int w    = t >> 6;
    const int lane = t & 63;
    const int quad = lane >> 4;
    const int l16  = lane & 15;

    __shared__ __align__(16) u16 smem[18688];   // 37376 B
    u16* Ks = smem;                // 32 x 264
    u16* Vs = smem + 8448;         // 256 x 40
    u16* Os = smem;                // epilogue reuse: 64 x 264

    f16x8 qf[8];
    {
        const size_t qrow = (size_t)(b * 2048 + q0 + w * 16 + l16) * 256;
#pragma unroll
        for (int kc = 0; kc < 8; ++kc)
            qf[kc] = *(const f16x8*)&Qh[qrow + kc * 32 + quad * 8];
    }

    f32x4 O[16];
#pragma unroll
    for (int i = 0; i < 16; ++i) O[i] = f32x4{0.f, 0.f, 0.f, 0.f};
    float mrow = -1e30f, lrow = 0.f;

    for (int it = 0; it < my_tiles; ++it) {
        const int kt = (tile0 + it) * 32;
#pragma unroll
        for (int i = 0; i < 4; ++i) {
            const int ch = i * 256 + t;
            const int row = ch >> 5, cg = ch & 31;
            const int prow = ((row >> 2) & 3) * 8 + (row >> 4) * 4 + (row & 3);
            *(int4*)&Ks[row * 264 + cg * 8] =
                *(const int4*)&Kg[(size_t)(b * 2048 + kt + prow) * 256 + cg * 8];
        }
#pragma unroll
        for (int i = 0; i < 4; ++i) {
            const int ch = i * 256 + t;
            const int row = ch >> 2, cg = ch & 3;
            *(int4*)&Vs[row * 40 + cg * 8] =
                *(const int4*)&Vt[(size_t)b * 524288 + (size_t)row * 2048 + kt + cg * 8];
        }
        __syncthreads();

        f32x4 S[2];
        S[0] = f32x4{0.f, 0.f, 0.f, 0.f};
        S[1] = f32x4{0.f, 0.f, 0.f, 0.f};
        __builtin_amdgcn_s_setprio(1);
#pragma unroll
        for (int kc = 0; kc < 8; ++kc) {
#pragma unroll
            for (int kn = 0; kn < 2; ++kn) {
                const f16x8 kf = *(const f16x8*)&Ks[(kn * 16 + l16) * 264 + kc * 32 + quad * 8];
                S[kn] = MFMA_F16(kf, qf[kc], S[kn], 0, 0, 0);
            }
        }
        __builtin_amdgcn_s_setprio(0);

        float mt = fmaxf(fmaxf(fmaxf(S[0][0], S[0][1]), fmaxf(S[0][2], S[0][3])),
                         fmaxf(fmaxf(S[1][0], S[1][1]), fmaxf(S[1][2], S[1][3])));
        mt = fmaxf(mt, __shfl_xor(mt, 16));
        mt = fmaxf(mt, __shfl_xor(mt, 32));
        // T13 defer-max: only rescale when the tile max grows past mrow+8.
        if (__any(mt - mrow > 8.f)) {
            const float mnew = fmaxf(mrow, mt);
            const float a = __expf(mrow - mnew);
            lrow *= a;
#pragma unroll
            for (int dv = 0; dv < 16; ++dv)
#pragma unroll
                for (int r = 0; r < 4; ++r) O[dv][r] *= a;
            mrow = mnew;
        }
        // fused exp -> sum -> f16 convert (no float p[][] array)
        f16x8 pfv;
        float s = 0.f;
#pragma unroll
        for (int kn = 0; kn < 2; ++kn)
#pragma unroll
            for (int r = 0; r < 4; ++r) {
                const float e = __expf(S[kn][r] - mrow);
                s += e;
                pfv[kn * 4 + r] = (_Float16)e;
            }
        s += __shfl_xor(s, 16);
        s += __shfl_xor(s, 32);
        lrow += s;

        __builtin_amdgcn_s_setprio(1);
#pragma unroll
        for (int dvt = 0; dvt < 16; ++dvt) {
            const f16x8 vf = *(const f16x8*)&Vs[(dvt * 16 + l16) * 40 + quad * 8];
            O[dvt] = MFMA_F16(vf, pfv, O[dvt], 0, 0, 0);
        }
        __builtin_amdgcn_s_setprio(0);
        __syncthreads();
    }

    {
        const float rl = 1.0f / lrow;
#pragma unroll
        for (int dvt = 0; dvt < 16; ++dvt) {
            ushort4 h4;
            h4.x = f2h(O[dvt][0] * rl);
            h4.y = f2h(O[dvt][1] * rl);
            h4.z = f2h(O[dvt][2] * rl);
            h4.w = f2h(O[dvt][3] * rl);
            *(ushort4*)&Os[(w * 16 + l16) * 264 + dvt * 16 + quad * 4] = h4;
        }
        if (quad == 0) {
            const int grow = b * 2048 + q0 + w * 16 + l16;
            lmpL[z * 16384 + grow] = lrow;
            lmpM[z * 16384 + grow] = mrow;
        }
    }
    __syncthreads();

    {
        const int row = t >> 2;
        if (z < 2) {
            u16* __restrict__ Oz = Op + (size_t)z * 4194304;
#pragma unroll
            for (int i = 0; i < 8; ++i) {
                const int chunk = (t & 3) * 8 + i;
                *(int4*)&Oz[(size_t)(b * 2048 + q0 + row) * 256 + chunk * 8] =
                    *(const int4*)&Os[row * 264 + chunk * 8];
            }
        } else {
            // z==2 packed into d_out scratch: row m -> u16[m*512 + 0..255]
            u16* __restrict__ Oz = OutS;
#pragma unroll
            for (int i = 0; i < 8; ++i) {
                const int chunk = (t & 3) * 8 + i;
                *(int4*)&Oz[(size_t)(b * 2048 + q0 + row) * 512 + chunk * 8] =
                    *(const int4*)&Os[row * 264 + chunk * 8];
            }
        }
    }
}

// ---------------------------------------------------------------------------
// Kernel 3: combine 3 partials + out projection + LayerNorm + LeakyReLU.
// R18: 32 rows/block, grid 512 = 2 blocks/CU (was 256 = 1/CU — the grid
// itself capped occupancy at 12.5%). 4 waves = 2 row-groups x 2 col-halves,
// acc[8] (was acc[16]). LN mean/var needs a cross-wave merge of the two
// 128-col halves: 512B LDS table + one extra barrier.
// Partial z=2 packed in d_out scratch; block reads rows m0..m0+31 fully in
// the k-loop before the epilogue overwrites exactly those rows (no hazard).
// ---------------------------------------------------------------------------
__global__ __launch_bounds__(256, 2) void outproj_ln(
    const u16* __restrict__ Op, const u16* __restrict__ OutS,
    const float* __restrict__ lmpL, const float* __restrict__ lmpM,
    const u16* __restrict__ Woh, const float* __restrict__ bo,
    const float* __restrict__ gamma, const float* __restrict__ beta,
    float* __restrict__ out)
{
    const int m0   = blockIdx.x * 32;
    const int t    = threadIdx.x;
    const int w    = t >> 6;
    const int rw   = w & 1;        // row-group (16 rows)
    const int cw   = w >> 1;       // col-half (128 cols)
    const int lane = t & 63;
    const int quad = lane >> 4;
    const int l16  = lane & 15;

    __shared__ __align__(16) u16 Ls[32 * 40];
    __shared__ __align__(16) u16 Ws[256 * 40];
    __shared__ _Float16 wls[3][32];
    __shared__ float part[2][16][2][2];   // [rw][row16][cw][{sh,sh2}]

    if (t < 32) {
        const float l0 = lmpL[m0 + t];
        const float l1 = lmpL[16384 + m0 + t];
        const float l2 = lmpL[32768 + m0 + t];
        const float m0v = lmpM[m0 + t];
        const float m1v = lmpM[16384 + m0 + t];
        const float m2v = lmpM[32768 + m0 + t];
        const float mm = fmaxf(fmaxf(m0v, m1v), m2v);
        const float u0 = l0 * __expf(m0v - mm);
        const float u1 = l1 * __expf(m1v - mm);
        const float u2 = l2 * __expf(m2v - mm);
        const float inv = 1.0f / (u0 + u1 + u2);
        wls[0][t] = (_Float16)(u0 * inv);
        wls[1][t] = (_Float16)(u1 * inv);
        wls[2][t] = (_Float16)(u2 * inv);
    }
    __syncthreads();

    f32x4 acc[8];
#pragma unroll
    for (int i = 0; i < 8; ++i) acc[i] = f32x4{0.f, 0.f, 0.f, 0.f};

    for (int kc = 0; kc < 8; ++kc) {
        if (t < 128) {
            const int row = t >> 2, cg = t & 3;
            const size_t off  = (size_t)(m0 + row) * 256 + kc * 32 + cg * 8;
            const size_t offS = (size_t)(m0 + row) * 512 + kc * 32 + cg * 8;
            const f16x8 o0 = __builtin_bit_cast(f16x8, *(const int4*)&Op[off]);
            const f16x8 o1 = __builtin_bit_cast(f16x8, *(const int4*)&Op[4194304 + off]);
            const f16x8 o2 = __builtin_bit_cast(f16x8, *(const int4*)&OutS[offS]);
            const _Float16 w0 = wls[0][row], w1 = wls[1][row], w2 = wls[2][row];
            f16x8 lw;
#pragma unroll
            for (int j = 0; j < 8; ++j)
                lw[j] = o0[j] * w0 + o1[j] * w1 + o2[j] * w2;
            *(int4*)&Ls[row * 40 + cg * 8] = __builtin_bit_cast(int4, lw);
        }
#pragma unroll
        for (int i = 0; i < 4; ++i) {
            const int ch = i * 256 + t;
            const int row = ch >> 2, cg = ch & 3;
            *(int4*)&Ws[row * 40 + cg * 8] =
                *(const int4*)&Woh[(size_t)row * 256 + kc * 32 + cg * 8];
        }
        __syncthreads();

        const f16x8 af = *(const f16x8*)&Ls[(rw * 16 + l16) * 40 + quad * 8];
#pragma unroll
        for (int nt = 0; nt < 8; ++nt) {
            const f16x8 bf = *(const f16x8*)&Ws[((cw * 8 + nt) * 16 + l16) * 40 + quad * 8];
            acc[nt] = MFMA_F16(af, bf, acc[nt], 0, 0, 0);
        }
        __syncthreads();
    }

    float g[8], bt[8], bb[8];
#pragma unroll
    for (int nt = 0; nt < 8; ++nt) {
        const int col = cw * 128 + nt * 16 + l16;
        bb[nt] = bo[col]; g[nt] = gamma[col]; bt[nt] = beta[col];
    }

    // pass 1: per-row 128-col partial sums, reduced across the 16 lanes
    float shv[4], sh2v[4];
#pragma unroll
    for (int r = 0; r < 4; ++r) {
        float sh = 0.f, sh2 = 0.f;
#pragma unroll
        for (int nt = 0; nt < 8; ++nt) {
            const float h = acc[nt][r] + bb[nt];
            sh  += h;
            sh2 += h * h;
        }
        sh  += __shfl_xor(sh, 1);  sh  += __shfl_xor(sh, 2);
        sh  += __shfl_xor(sh, 4);  sh  += __shfl_xor(sh, 8);
        sh2 += __shfl_xor(sh2, 1); sh2 += __shfl_xor(sh2, 2);
        sh2 += __shfl_xor(sh2, 4); sh2 += __shfl_xor(sh2, 8);
        shv[r] = sh; sh2v[r] = sh2;
    }
    if (l16 == 0) {
#pragma unroll
        for (int r = 0; r < 4; ++r) {
            part[rw][quad * 4 + r][cw][0] = shv[r];
            part[rw][quad * 4 + r][cw][1] = sh2v[r];
        }
    }
    __syncthreads();

    // pass 2: merge the partner col-half, LN, LeakyReLU, store
#pragma unroll
    for (int r = 0; r < 4; ++r) {
        const float sh  = shv[r]  + part[rw][quad * 4 + r][cw ^ 1][0];
        const float sh2 = sh2v[r] + part[rw][quad * 4 + r][cw ^ 1][1];
        const float mu  = sh * (1.f / 256.f);
        const float var = fmaxf(sh2 * (1.f / 256.f) - mu * mu, 0.f);
        const float rs  = rsqrtf(var + 1e-5f);
        const size_t row = (size_t)(m0 + rw * 16 + quad * 4 + r) * 256;
#pragma unroll
        for (int nt = 0; nt < 8; ++nt) {
            const float hn = (acc[nt][r] + bb[nt] - mu) * rs * g[nt] + bt[nt];
            out[row + cw * 128 + nt * 16 + l16] = (hn >= 0.f) ? hn : 0.01f * hn;
        }
    }
}

// ---------------------------------------------------------------------------
extern "C" void kernel_launch(void* const* d_in, const int* in_sizes, int n_in,
                              void* d_out, int out_size, void* d_ws, size_t ws_size,
                              hipStream_t stream)
{
    const float* x  = (const float*)d_in[0];
    const float* Wq = (const float*)d_in[1];
    const float* bq = (const float*)d_in[2];
    const float* Wk = (const float*)d_in[3];
    const float* bk = (const float*)d_in[4];
    const float* Wv = (const float*)d_in[5];
    const float* bv = (const float*)d_in[6];
    const float* Wo = (const float*)d_in[7];
    const float* bo = (const float*)d_in[8];
    const float* gm = (const float*)d_in[9];
    const float* bt = (const float*)d_in[10];
    float* out = (float*)d_out;

    // ws layout (u16): [W4 262144][Qh 4.19M][Kh 4.19M][Vt 4.19M][Op 2x4.19M][lmpM]
    // -> identical total d_ws footprint to the 199µs baseline.
    // l-stats (l[3][16384] f32) live in the dead Wq/Wk/Wv half of W4
    // (first 196608 u16 = 384KB, dead after proj_qkv; Woh at +196608 intact).
    // split-K partial z=2 lives packed inside d_out (scratch until outproj).
    u16* W4 = (u16*)d_ws;
    u16* Qh = W4 + 262144;
    u16* Kh = Qh + 4194304;
    u16* Vt = Kh + 4194304;
    u16* Op = Vt + 4194304;
    float* lmpM = (float*)(Op + 2 * 4194304);  // m[3][16384] (old lmp slot)
    float* lmpL = (float*)W4;                  // l[3][16384] (dead W region)
    u16* Woh = W4 + 196608;
    u16* OutS = (u16*)d_out;

    prep_w     <<<64,             256, 0, stream>>>(Wq, Wk, Wv, Wo, W4);
    proj_qkv   <<<dim3(256, 3),   256, 0, stream>>>(x, W4, bq, bk, bv, Qh, Kh, Vt);
    attn       <<<dim3(32, 8, 3), 256, 0, stream>>>(Qh, Kh, Vt, Op, OutS, lmpL, lmpM);
    outproj_ln <<<512,            256, 0, stream>>>(Op, OutS, lmpL, lmpM, Woh, bo, gm, bt, out);
}

// Round 7
// 170.720 us; speedup vs baseline: 1.7957x; 1.0393x over previous
//
#include <hip/hip_runtime.h>

typedef unsigned short u16;
typedef __attribute__((ext_vector_type(8))) _Float16 f16x8;
typedef __attribute__((ext_vector_type(4))) float f32x4;

#define MFMA_F16 __builtin_amdgcn_mfma_f32_16x16x32_f16

static __device__ __forceinline__ u16 f2h(float f) {
    return __builtin_bit_cast(u16, (_Float16)f);
}
static __device__ __forceinline__ ushort4 f4_to_h4(const float4 v) {
    ushort4 r;
    r.x = f2h(v.x); r.y = f2h(v.y); r.z = f2h(v.z); r.w = f2h(v.w);
    return r;
}
// async global->LDS, 16B per lane, dest = wave-uniform base + lane*16
static __device__ __forceinline__ void gl16(const u16* g, u16* l) {
    __builtin_amdgcn_global_load_lds(
        (__attribute__((address_space(1))) void*)(g),
        (__attribute__((address_space(3))) void*)(l),
        16, 0, 0);
}

// ---------------------------------------------------------------------------
// Kernel 0: prep_w — convert Wq/Wk/Wv/Wo (4 x 16384 float4) fp32 -> fp16.
// ---------------------------------------------------------------------------
__global__ __launch_bounds__(256) void prep_w(
    const float* __restrict__ wq, const float* __restrict__ wk,
    const float* __restrict__ wv, const float* __restrict__ wo,
    u16* __restrict__ w4)
{
    const int tid = blockIdx.x * 256 + threadIdx.x;   // 16384 threads
    for (int i = tid; i < 65536; i += 16384) {
        const float* src = (i < 16384) ? wq : (i < 32768) ? wk
                         : (i < 49152) ? wv : wo;
        ((ushort4*)w4)[i] = f4_to_h4(((const float4*)src)[i & 16383]);
    }
}

// ---------------------------------------------------------------------------
// Kernel 1: Q/K/V projection, fp16 MFMA (R18, measured good — unchanged).
// ---------------------------------------------------------------------------
__global__ __launch_bounds__(256, 3) void proj_qkv(
    const float* __restrict__ X, const u16* __restrict__ w4,
    const float* __restrict__ bq, const float* __restrict__ bk,
    const float* __restrict__ bv,
    u16* __restrict__ Qh, u16* __restrict__ Kh, u16* __restrict__ Vt)
{
    const int z = blockIdx.y;
    const u16* __restrict__ W     = w4 + z * 65536;
    const float* __restrict__ bias = (z == 0) ? bq : (z == 1) ? bk : bv;

    const int m0   = blockIdx.x * 64;          // global row (b*2048 + n0)
    const int t    = threadIdx.x;
    const int w    = t >> 6;
    const int lane = t & 63;
    const int quad = lane >> 4;
    const int l16  = lane & 15;

    __shared__ __align__(16) u16 smem[18432];  // 36864 B
    u16* Xs = smem;            // 64 x 40 during k-loop
    u16* Ws = smem + 2560;     // 256 x 40 during k-loop

    f32x4 acc[16];
#pragma unroll
    for (int i = 0; i < 16; ++i) acc[i] = f32x4{0.f, 0.f, 0.f, 0.f};

    for (int kc = 0; kc < 8; ++kc) {
#pragma unroll
        for (int i = 0; i < 2; ++i) {
            const int ch = i * 256 + t;
            const int row = ch >> 3, cg = ch & 7;
            const float4 v = *(const float4*)&X[(size_t)(m0 + row) * 256 + kc * 32 + cg * 4];
            *(ushort4*)&Xs[row * 40 + cg * 4] = f4_to_h4(v);
        }
#pragma unroll
        for (int i = 0; i < 4; ++i) {
            const int ch = i * 256 + t;
            const int row = ch >> 2, cg = ch & 3;
            *(int4*)&Ws[row * 40 + cg * 8] =
                *(const int4*)&W[(size_t)row * 256 + kc * 32 + cg * 8];
        }
        __syncthreads();

        const f16x8 af = *(const f16x8*)&Xs[(w * 16 + l16) * 40 + quad * 8];
#pragma unroll
        for (int nt = 0; nt < 16; ++nt) {
            const f16x8 bf = *(const f16x8*)&Ws[(nt * 16 + l16) * 40 + quad * 8];
            acc[nt] = MFMA_F16(af, bf, acc[nt], 0, 0, 0);
        }
        __syncthreads();
    }

    if (z < 2) {
        u16* __restrict__ Y = (z == 0) ? Qh : Kh;
#pragma unroll
        for (int nt = 0; nt < 16; ++nt) {
            const int col = nt * 16 + l16;
            const float bb = bias[col];
#pragma unroll
            for (int r = 0; r < 4; ++r)
                smem[(w * 16 + quad * 4 + r) * 264 + col] = f2h(acc[nt][r] + bb);
        }
        __syncthreads();
#pragma unroll
        for (int i = 0; i < 8; ++i) {
            const int ch = i * 256 + t;
            const int row = ch >> 5, cg = ch & 31;
            *(int4*)&Y[(size_t)(m0 + row) * 256 + cg * 8] =
                *(const int4*)&smem[row * 264 + cg * 8];
        }
    } else {
        const int b  = m0 >> 11;
        const int n0 = m0 & 2047;
#pragma unroll
        for (int nt = 0; nt < 16; ++nt) {
            const int col = nt * 16 + l16;
            const float bb = bias[col];
            ushort4 h4;
            h4.x = f2h(acc[nt][0] + bb);
            h4.y = f2h(acc[nt][1] + bb);
            h4.z = f2h(acc[nt][2] + bb);
            h4.w = f2h(acc[nt][3] + bb);
            *(ushort4*)&smem[col * 72 + w * 16 + quad * 4] = h4;
        }
        __syncthreads();
#pragma unroll
        for (int i = 0; i < 8; ++i) {
            const int ch = i * 256 + t;
            const int row = ch >> 3, cg = ch & 7;
            *(int4*)&Vt[(size_t)b * 524288 + (size_t)row * 2048 + n0 + cg * 8] =
                *(const int4*)&smem[row * 72 + cg * 8];
        }
    }
}

// ---------------------------------------------------------------------------
// Kernel 2: flash attention. R19: global_load_lds double-buffered pipeline.
// attn is serialization-bound (all pipes <25%); R15 showed reg-staged
// pipelining spills. gload_lds stages direct to LDS (no VGPRs), double
// buffer (64KB -> 2 blocks/CU, nz=2 -> grid 512 = exactly 2/CU), raw
// s_barrier + manual vmcnt (hipcc's __syncthreads drains vmcnt(0) and
// would kill the pipeline). ONE barrier per tile:
//   vmcnt(0); s_barrier; STAGE(next -> buf^1); compute(buf)
// gload_lds needs linear LDS (no padding), so bank conflicts are fixed by
// XOR swizzle applied on BOTH sides (source chunk index at stage, chunk
// index at read — same involution, rule 21):
//   K: 32 rows x 512B, chunk c in 0..31, c ^= (row&7)   -> kf reads ~2-way
//   V: 128 rows x 128B (2 d-rows packed), c in 0..3, c ^= ((d>>1)&3)
// defer-max (T13), setprio (T5), fused exp kept from R17.
// ---------------------------------------------------------------------------
__global__ __launch_bounds__(256, 2) void attn(
    const u16* __restrict__ Qh, const u16* __restrict__ Kg,
    const u16* __restrict__ Vt, u16* __restrict__ Op, float* __restrict__ lmp)
{
    const int nz = gridDim.z;          // 2
    const int z  = blockIdx.z;
    const int ntiles = 32;             // 64 tiles / nz
    const int tile0  = ntiles * z;

    const int b  = blockIdx.y;
    const int q0 = blockIdx.x * 64;
    const int t    = threadIdx.x;
    const int w    = t >> 6;
    const int lane = t & 63;
    const int quad = lane >> 4;
    const int l16  = lane & 15;

    // [K0 8192][V0 8192][K1 8192][V1 8192] u16 = 65536 B
    __shared__ __align__(16) u16 smem[32768];
    u16* Os = smem;                // epilogue reuse: 64 x 264 (16896 u16)

    f16x8 qf[8];
    {
        const size_t qrow = (size_t)(b * 2048 + q0 + w * 16 + l16) * 256;
#pragma unroll
        for (int kc = 0; kc < 8; ++kc)
            qf[kc] = *(const f16x8*)&Qh[qrow + kc * 32 + quad * 8];
    }

    // per-thread staging source bases (tile-invariant, u16 indices)
    unsigned kgb[4], vgb[4];
#pragma unroll
    for (int i = 0; i < 4; ++i) {
        const int j  = w * 4 + i;
        const int r  = 2 * j + (lane >> 5);                 // K LDS row 0..31
        const int pr = ((r >> 2) & 3) * 8 + (r >> 4) * 4 + (r & 3);
        const int c  = lane & 31;                           // 16B chunk in row
        kgb[i] = (unsigned)((b * 2048 + pr) * 256 + ((c ^ (r & 7)) * 8));
        const int rp = 8 * j + (lane >> 3);                 // V LDS row 0..127
        const int c8 = lane & 7;                            // 16B chunk in row
        const int d  = 2 * rp + (c8 >> 2);                  // d-row 0..255
        const int a  = (c8 & 3) ^ (rp & 3);                 // actual key-chunk
        vgb[i] = (unsigned)(b * 524288 + d * 2048 + a * 8);
    }

#define STAGE(bufsel, kt_) do {                                              \
        u16* Kb_ = smem + (bufsel) * 16384;                                  \
        u16* Vb_ = Kb_ + 8192;                                               \
        _Pragma("unroll")                                                    \
        for (int i_ = 0; i_ < 4; ++i_) {                                     \
            gl16(Kg + kgb[i_] + (unsigned)(kt_) * 256,                       \
                 Kb_ + (w * 4 + i_) * 512);                                  \
            gl16(Vt + vgb[i_] + (unsigned)(kt_),                             \
                 Vb_ + (w * 4 + i_) * 512);                                  \
        }                                                                    \
    } while (0)

    f32x4 O[16];
#pragma unroll
    for (int i = 0; i < 16; ++i) O[i] = f32x4{0.f, 0.f, 0.f, 0.f};
    float mrow = -1e30f, lrow = 0.f;

    // V read base (thread-invariant part)
    const int vbase = (l16 >> 1) * 64 + (l16 & 1) * 32
                    + ((quad ^ ((l16 >> 1) & 3)) * 8);

    STAGE(0, tile0 * 32);

    for (int it = 0; it < ntiles; ++it) {
        asm volatile("s_waitcnt vmcnt(0)" ::: "memory");
        __builtin_amdgcn_s_barrier();
        __builtin_amdgcn_sched_barrier(0);
        if (it + 1 < ntiles) STAGE((it + 1) & 1, (tile0 + it + 1) * 32);
        __builtin_amdgcn_sched_barrier(0);

        const u16* Kc = smem + (it & 1) * 16384;
        const u16* Vc = Kc + 8192;

        f32x4 S[2];
        S[0] = f32x4{0.f, 0.f, 0.f, 0.f};
        S[1] = f32x4{0.f, 0.f, 0.f, 0.f};
        __builtin_amdgcn_s_setprio(1);
#pragma unroll
        for (int kc = 0; kc < 8; ++kc) {
#pragma unroll
            for (int kn = 0; kn < 2; ++kn) {
                const int r2 = kn * 16 + l16;
                const f16x8 kf = *(const f16x8*)
                    &Kc[r2 * 256 + (((kc * 4 + quad) ^ (l16 & 7)) * 8)];
                S[kn] = MFMA_F16(kf, qf[kc], S[kn], 0, 0, 0);
            }
        }
        __builtin_amdgcn_s_setprio(0);

        float mt = fmaxf(fmaxf(fmaxf(S[0][0], S[0][1]), fmaxf(S[0][2], S[0][3])),
                         fmaxf(fmaxf(S[1][0], S[1][1]), fmaxf(S[1][2], S[1][3])));
        mt = fmaxf(mt, __shfl_xor(mt, 16));
        mt = fmaxf(mt, __shfl_xor(mt, 32));
        // T13 defer-max: rescale only when tile max grows past mrow+8.
        if (__any(mt - mrow > 8.f)) {
            const float mnew = fmaxf(mrow, mt);
            const float a = __expf(mrow - mnew);
            lrow *= a;
#pragma unroll
            for (int dv = 0; dv < 16; ++dv)
#pragma unroll
                for (int r = 0; r < 4; ++r) O[dv][r] *= a;
            mrow = mnew;
        }
        f16x8 pfv;
        float s = 0.f;
#pragma unroll
        for (int kn = 0; kn < 2; ++kn)
#pragma unroll
            for (int r = 0; r < 4; ++r) {
                const float e = __expf(S[kn][r] - mrow);
                s += e;
                pfv[kn * 4 + r] = (_Float16)e;
            }
        s += __shfl_xor(s, 16);
        s += __shfl_xor(s, 32);
        lrow += s;

        __builtin_amdgcn_s_setprio(1);
#pragma unroll
        for (int dvt = 0; dvt < 16; ++dvt) {
            const f16x8 vf = *(const f16x8*)&Vc[dvt * 512 + vbase];
            O[dvt] = MFMA_F16(vf, pfv, O[dvt], 0, 0, 0);
        }
        __builtin_amdgcn_s_setprio(0);
    }
#undef STAGE

    __syncthreads();   // all waves done with last tile before smem reuse
    {
        const float rl = 1.0f / lrow;
#pragma unroll
        for (int dvt = 0; dvt < 16; ++dvt) {
            ushort4 h4;
            h4.x = f2h(O[dvt][0] * rl);
            h4.y = f2h(O[dvt][1] * rl);
            h4.z = f2h(O[dvt][2] * rl);
            h4.w = f2h(O[dvt][3] * rl);
            *(ushort4*)&Os[(w * 16 + l16) * 264 + dvt * 16 + quad * 4] = h4;
        }
        if (quad == 0) {
            const int grow = b * 2048 + q0 + w * 16 + l16;
            lmp[z * 16384 + grow]        = lrow;
            lmp[(nz + z) * 16384 + grow] = mrow;
        }
    }
    __syncthreads();

    u16* __restrict__ Oz = Op + (size_t)z * 4194304;
    {
        const int row = t >> 2;
#pragma unroll
        for (int i = 0; i < 8; ++i) {
            const int chunk = (t & 3) * 8 + i;
            *(int4*)&Oz[(size_t)(b * 2048 + q0 + row) * 256 + chunk * 8] =
                *(const int4*)&Os[row * 264 + chunk * 8];
        }
    }
}

// ---------------------------------------------------------------------------
// Kernel 3: combine 2 partials + out projection + LayerNorm + LeakyReLU.
// R18 structure (32 rows/block, 512 blocks = 2/CU, cross-wave LN merge),
// adapted back to 2 partials (nz=2).
// ---------------------------------------------------------------------------
__global__ __launch_bounds__(256, 2) void outproj_ln(
    const u16* __restrict__ Op, const float* __restrict__ lmp,
    const u16* __restrict__ Woh, const float* __restrict__ bo,
    const float* __restrict__ gamma, const float* __restrict__ beta,
    float* __restrict__ out)
{
    const int m0   = blockIdx.x * 32;
    const int t    = threadIdx.x;
    const int w    = t >> 6;
    const int rw   = w & 1;        // row-group (16 rows)
    const int cw   = w >> 1;       // col-half (128 cols)
    const int lane = t & 63;
    const int quad = lane >> 4;
    const int l16  = lane & 15;

    __shared__ __align__(16) u16 Ls[32 * 40];
    __shared__ __align__(16) u16 Ws[256 * 40];
    __shared__ _Float16 wls[2][32];
    __shared__ float part[2][16][2][2];   // [rw][row16][cw][{sh,sh2}]

    if (t < 32) {
        const float l0 = lmp[m0 + t],          l1 = lmp[16384 + m0 + t];
        const float mm0 = lmp[32768 + m0 + t], mm1 = lmp[49152 + m0 + t];
        const float mm = fmaxf(mm0, mm1);
        const float u0 = l0 * __expf(mm0 - mm);
        const float u1 = l1 * __expf(mm1 - mm);
        const float inv = 1.0f / (u0 + u1);
        wls[0][t] = (_Float16)(u0 * inv);
        wls[1][t] = (_Float16)(u1 * inv);
    }
    __syncthreads();

    f32x4 acc[8];
#pragma unroll
    for (int i = 0; i < 8; ++i) acc[i] = f32x4{0.f, 0.f, 0.f, 0.f};

    for (int kc = 0; kc < 8; ++kc) {
        if (t < 128) {
            const int row = t >> 2, cg = t & 3;
            const size_t off = (size_t)(m0 + row) * 256 + kc * 32 + cg * 8;
            const f16x8 o0 = __builtin_bit_cast(f16x8, *(const int4*)&Op[off]);
            const f16x8 o1 = __builtin_bit_cast(f16x8, *(const int4*)&Op[4194304 + off]);
            const _Float16 w0 = wls[0][row], w1 = wls[1][row];
            f16x8 lw;
#pragma unroll
            for (int j = 0; j < 8; ++j) lw[j] = o0[j] * w0 + o1[j] * w1;
            *(int4*)&Ls[row * 40 + cg * 8] = __builtin_bit_cast(int4, lw);
        }
#pragma unroll
        for (int i = 0; i < 4; ++i) {
            const int ch = i * 256 + t;
            const int row = ch >> 2, cg = ch & 3;
            *(int4*)&Ws[row * 40 + cg * 8] =
                *(const int4*)&Woh[(size_t)row * 256 + kc * 32 + cg * 8];
        }
        __syncthreads();

        const f16x8 af = *(const f16x8*)&Ls[(rw * 16 + l16) * 40 + quad * 8];
#pragma unroll
        for (int nt = 0; nt < 8; ++nt) {
            const f16x8 bf = *(const f16x8*)&Ws[((cw * 8 + nt) * 16 + l16) * 40 + quad * 8];
            acc[nt] = MFMA_F16(af, bf, acc[nt], 0, 0, 0);
        }
        __syncthreads();
    }

    float g[8], bt[8], bb[8];
#pragma unroll
    for (int nt = 0; nt < 8; ++nt) {
        const int col = cw * 128 + nt * 16 + l16;
        bb[nt] = bo[col]; g[nt] = gamma[col]; bt[nt] = beta[col];
    }

    float shv[4], sh2v[4];
#pragma unroll
    for (int r = 0; r < 4; ++r) {
        float sh = 0.f, sh2 = 0.f;
#pragma unroll
        for (int nt = 0; nt < 8; ++nt) {
            const float h = acc[nt][r] + bb[nt];
            sh  += h;
            sh2 += h * h;
        }
        sh  += __shfl_xor(sh, 1);  sh  += __shfl_xor(sh, 2);
        sh  += __shfl_xor(sh, 4);  sh  += __shfl_xor(sh, 8);
        sh2 += __shfl_xor(sh2, 1); sh2 += __shfl_xor(sh2, 2);
        sh2 += __shfl_xor(sh2, 4); sh2 += __shfl_xor(sh2, 8);
        shv[r] = sh; sh2v[r] = sh2;
    }
    if (l16 == 0) {
#pragma unroll
        for (int r = 0; r < 4; ++r) {
            part[rw][quad * 4 + r][cw][0] = shv[r];
            part[rw][quad * 4 + r][cw][1] = sh2v[r];
        }
    }
    __syncthreads();

#pragma unroll
    for (int r = 0; r < 4; ++r) {
        const float sh  = shv[r]  + part[rw][quad * 4 + r][cw ^ 1][0];
        const float sh2 = sh2v[r] + part[rw][quad * 4 + r][cw ^ 1][1];
        const float mu  = sh * (1.f / 256.f);
        const float var = fmaxf(sh2 * (1.f / 256.f) - mu * mu, 0.f);
        const float rs  = rsqrtf(var + 1e-5f);
        const size_t row = (size_t)(m0 + rw * 16 + quad * 4 + r) * 256;
#pragma unroll
        for (int nt = 0; nt < 8; ++nt) {
            const float hn = (acc[nt][r] + bb[nt] - mu) * rs * g[nt] + bt[nt];
            out[row + cw * 128 + nt * 16 + l16] = (hn >= 0.f) ? hn : 0.01f * hn;
        }
    }
}

// ---------------------------------------------------------------------------
extern "C" void kernel_launch(void* const* d_in, const int* in_sizes, int n_in,
                              void* d_out, int out_size, void* d_ws, size_t ws_size,
                              hipStream_t stream)
{
    const float* x  = (const float*)d_in[0];
    const float* Wq = (const float*)d_in[1];
    const float* bq = (const float*)d_in[2];
    const float* Wk = (const float*)d_in[3];
    const float* bk = (const float*)d_in[4];
    const float* Wv = (const float*)d_in[5];
    const float* bv = (const float*)d_in[6];
    const float* Wo = (const float*)d_in[7];
    const float* bo = (const float*)d_in[8];
    const float* gm = (const float*)d_in[9];
    const float* bt = (const float*)d_in[10];
    float* out = (float*)d_out;

    // ws layout (u16): [W4 262144][Qh 4.19M][Kh 4.19M][Vt 4.19M][Op 2x4.19M][lmp]
    // (identical footprint to the 199µs baseline)
    u16* W4 = (u16*)d_ws;
    u16* Qh = W4 + 262144;
    u16* Kh = Qh + 4194304;
    u16* Vt = Kh + 4194304;
    u16* Op = Vt + 4194304;
    float* lmp = (float*)(Op + 2 * 4194304);  // l[2][16384], m[2][16384]
    u16* Woh = W4 + 196608;

    prep_w     <<<64,             256, 0, stream>>>(Wq, Wk, Wv, Wo, W4);
    proj_qkv   <<<dim3(256, 3),   256, 0, stream>>>(x, W4, bq, bk, bv, Qh, Kh, Vt);
    attn       <<<dim3(32, 8, 2), 256, 0, stream>>>(Qh, Kh, Vt, Op, lmp);
    outproj_ln <<<512,            256, 0, stream>>>(Op, lmp, Woh, bo, gm, bt, out);
}

// Round 8
// 167.339 us; speedup vs baseline: 1.8320x; 1.0202x over previous
//
#include <hip/hip_runtime.h>

typedef unsigned short u16;
typedef __attribute__((ext_vector_type(8))) _Float16 f16x8;
typedef __attribute__((ext_vector_type(4))) float f32x4;

#define MFMA_F16 __builtin_amdgcn_mfma_f32_16x16x32_f16

static __device__ __forceinline__ u16 f2h(float f) {
    return __builtin_bit_cast(u16, (_Float16)f);
}
static __device__ __forceinline__ ushort4 f4_to_h4(const float4 v) {
    ushort4 r;
    r.x = f2h(v.x); r.y = f2h(v.y); r.z = f2h(v.z); r.w = f2h(v.w);
    return r;
}
// async global->LDS, 16B per lane, dest = wave-uniform base + lane*16
static __device__ __forceinline__ void gl16(const u16* g, u16* l) {
    __builtin_amdgcn_global_load_lds(
        (__attribute__((address_space(1))) void*)(g),
        (__attribute__((address_space(3))) void*)(l),
        16, 0, 0);
}

// ---------------------------------------------------------------------------
// Kernel 0: prep_w — convert Wq/Wk/Wv/Wo fp32->fp16 AND X fp32->fp16 (Xh,
// R20: one-time conversion so proj_qkv never touches fp32 X or the VALU
// convert; Xh lives in d_out scratch, overwritten only by outproj at the end).
// ---------------------------------------------------------------------------
__global__ __launch_bounds__(256) void prep_w(
    const float* __restrict__ wq, const float* __restrict__ wk,
    const float* __restrict__ wv, const float* __restrict__ wo,
    const float* __restrict__ x,
    u16* __restrict__ w4, u16* __restrict__ xh)
{
    const int tid = blockIdx.x * 256 + threadIdx.x;   // 65536 threads
    {
        const float* src = (tid < 16384) ? wq : (tid < 32768) ? wk
                         : (tid < 49152) ? wv : wo;
        ((ushort4*)w4)[tid] = f4_to_h4(((const float4*)src)[tid & 16383]);
    }
#pragma unroll
    for (int i = 0; i < 16; ++i) {
        const int j = i * 65536 + tid;                // 1048576 float4 of X
        ((ushort4*)xh)[j] = f4_to_h4(((const float4*)x)[j]);
    }
}

// ---------------------------------------------------------------------------
// Kernel 1: Q/K/V projection. R20: rebuilt on the R19 pipeline template.
// Double-buffered gload_lds staging (X tile 4KB + W tile 16KB per buffer,
// 40KB total LDS -> 3 blocks/CU), raw s_barrier + vmcnt(0) at phase top,
// ONE barrier per k-step, loads in flight across the whole compute phase.
// Linear LDS rows (gload_lds requirement); bank conflicts fixed by XOR
// swizzle on BOTH sides (rule 21): 16B chunk position p holds data chunk
// c = p ^ ((row>>1)&3); MFMA reads position quad ^ ((l16>>1)&3) (row-term
// vanishes since rows are ×16) -> 2-way conflict = free.
// ---------------------------------------------------------------------------
__global__ __launch_bounds__(256, 3) void proj_qkv(
    const u16* __restrict__ Xh, const u16* __restrict__ w4,
    const float* __restrict__ bq, const float* __restrict__ bk,
    const float* __restrict__ bv,
    u16* __restrict__ Qh, u16* __restrict__ Kh, u16* __restrict__ Vt)
{
    const int z = blockIdx.y;
    const u16* __restrict__ W     = w4 + z * 65536;
    const float* __restrict__ bias = (z == 0) ? bq : (z == 1) ? bk : bv;

    const int m0   = blockIdx.x * 64;          // global row (b*2048 + n0)
    const int t    = threadIdx.x;
    const int w    = t >> 6;
    const int lane = t & 63;
    const int quad = lane >> 4;
    const int l16  = lane & 15;

    // [X 2048 u16][W 8192 u16] per buffer x 2 = 20480 u16 (40960 B)
    __shared__ __align__(16) u16 smem[20480];

    // staging source indices (u16), tile-invariant parts
    const int xrow = t >> 2, xpp = t & 3;
    const unsigned xsrc = (unsigned)((m0 + xrow) * 256
                        + ((xpp ^ ((xrow >> 1) & 3)) * 8));
    unsigned wsrc[4];
#pragma unroll
    for (int i = 0; i < 4; ++i) {
        const int j = i * 256 + t;
        const int row = j >> 2, p = j & 3;
        wsrc[i] = (unsigned)(row * 256 + ((p ^ ((row >> 1) & 3)) * 8));
    }

#define PSTAGE(bufsel, kc_) do {                                             \
        u16* B_ = smem + (bufsel) * 10240;                                   \
        gl16(Xh + xsrc + (unsigned)(kc_) * 32, B_ + w * 512);                \
        _Pragma("unroll")                                                    \
        for (int i_ = 0; i_ < 4; ++i_)                                       \
            gl16(W + wsrc[i_] + (unsigned)(kc_) * 32,                        \
                 B_ + 2048 + i_ * 2048 + w * 512);                           \
    } while (0)

    f32x4 acc[16];
#pragma unroll
    for (int i = 0; i < 16; ++i) acc[i] = f32x4{0.f, 0.f, 0.f, 0.f};

    const int rp = (quad ^ ((l16 >> 1) & 3)) * 8;   // swizzled read offset

    PSTAGE(0, 0);

    for (int kc = 0; kc < 8; ++kc) {
        asm volatile("s_waitcnt vmcnt(0)" ::: "memory");
        __builtin_amdgcn_s_barrier();
        __builtin_amdgcn_sched_barrier(0);
        if (kc + 1 < 8) PSTAGE((kc + 1) & 1, kc + 1);
        __builtin_amdgcn_sched_barrier(0);

        const u16* Xb = smem + (kc & 1) * 10240;
        const u16* Wb = Xb + 2048;

        const f16x8 af = *(const f16x8*)&Xb[(w * 16 + l16) * 32 + rp];
        __builtin_amdgcn_s_setprio(1);
#pragma unroll
        for (int nt = 0; nt < 16; ++nt) {
            const f16x8 bf = *(const f16x8*)&Wb[(nt * 16 + l16) * 32 + rp];
            acc[nt] = MFMA_F16(af, bf, acc[nt], 0, 0, 0);
        }
        __builtin_amdgcn_s_setprio(0);
    }
#undef PSTAGE

    __syncthreads();   // all waves done with LDS before epilogue reuse

    if (z < 2) {
        u16* __restrict__ Y = (z == 0) ? Qh : Kh;
        // C-layout -> Ds[n][d] (scalar u16 stores, block-local)
#pragma unroll
        for (int nt = 0; nt < 16; ++nt) {
            const int col = nt * 16 + l16;
            const float bb = bias[col];
#pragma unroll
            for (int r = 0; r < 4; ++r)
                smem[(w * 16 + quad * 4 + r) * 264 + col] = f2h(acc[nt][r] + bb);
        }
        __syncthreads();
        // coalesced row-major stores: 64 rows x 32 int4 = 2048 chunks
#pragma unroll
        for (int i = 0; i < 8; ++i) {
            const int ch = i * 256 + t;
            const int row = ch >> 5, cg = ch & 31;
            *(int4*)&Y[(size_t)(m0 + row) * 256 + cg * 8] =
                *(const int4*)&smem[row * 264 + cg * 8];
        }
    } else {
        // C-layout -> Dt[d][n] (ushort4 over r), then coalesced Vt rows
        const int b  = m0 >> 11;
        const int n0 = m0 & 2047;
#pragma unroll
        for (int nt = 0; nt < 16; ++nt) {
            const int col = nt * 16 + l16;
            const float bb = bias[col];
            ushort4 h4;
            h4.x = f2h(acc[nt][0] + bb);
            h4.y = f2h(acc[nt][1] + bb);
            h4.z = f2h(acc[nt][2] + bb);
            h4.w = f2h(acc[nt][3] + bb);
            *(ushort4*)&smem[col * 72 + w * 16 + quad * 4] = h4;
        }
        __syncthreads();
#pragma unroll
        for (int i = 0; i < 8; ++i) {
            const int ch = i * 256 + t;
            const int row = ch >> 3, cg = ch & 7;
            *(int4*)&Vt[(size_t)b * 524288 + (size_t)row * 2048 + n0 + cg * 8] =
                *(const int4*)&smem[row * 72 + cg * 8];
        }
    }
}

// ---------------------------------------------------------------------------
// Kernel 2: flash attention (R19, measured 63.3µs — UNCHANGED).
// gload_lds double-buffered pipeline, raw s_barrier + vmcnt(0), XOR swizzle
// both sides, defer-max (T13), setprio (T5), nz=2.
// ---------------------------------------------------------------------------
__global__ __launch_bounds__(256, 2) void attn(
    const u16* __restrict__ Qh, const u16* __restrict__ Kg,
    const u16* __restrict__ Vt, u16* __restrict__ Op, float* __restrict__ lmp)
{
    const int nz = gridDim.z;          // 2
    const int z  = blockIdx.z;
    const int ntiles = 32;             // 64 tiles / nz
    const int tile0  = ntiles * z;

    const int b  = blockIdx.y;
    const int q0 = blockIdx.x * 64;
    const int t    = threadIdx.x;
    const int w    = t >> 6;
    const int lane = t & 63;
    const int quad = lane >> 4;
    const int l16  = lane & 15;

    // [K0 8192][V0 8192][K1 8192][V1 8192] u16 = 65536 B
    __shared__ __align__(16) u16 smem[32768];
    u16* Os = smem;                // epilogue reuse: 64 x 264 (16896 u16)

    f16x8 qf[8];
    {
        const size_t qrow = (size_t)(b * 2048 + q0 + w * 16 + l16) * 256;
#pragma unroll
        for (int kc = 0; kc < 8; ++kc)
            qf[kc] = *(const f16x8*)&Qh[qrow + kc * 32 + quad * 8];
    }

    // per-thread staging source bases (tile-invariant, u16 indices)
    unsigned kgb[4], vgb[4];
#pragma unroll
    for (int i = 0; i < 4; ++i) {
        const int j  = w * 4 + i;
        const int r  = 2 * j + (lane >> 5);                 // K LDS row 0..31
        const int pr = ((r >> 2) & 3) * 8 + (r >> 4) * 4 + (r & 3);
        const int c  = lane & 31;                           // 16B chunk in row
        kgb[i] = (unsigned)((b * 2048 + pr) * 256 + ((c ^ (r & 7)) * 8));
        const int rp2 = 8 * j + (lane >> 3);                // V LDS row 0..127
        const int c8 = lane & 7;                            // 16B chunk in row
        const int d  = 2 * rp2 + (c8 >> 2);                 // d-row 0..255
        const int a  = (c8 & 3) ^ (rp2 & 3);                // actual key-chunk
        vgb[i] = (unsigned)(b * 524288 + d * 2048 + a * 8);
    }

#define STAGE(bufsel, kt_) do {                                              \
        u16* Kb_ = smem + (bufsel) * 16384;                                  \
        u16* Vb_ = Kb_ + 8192;                                               \
        _Pragma("unroll")                                                    \
        for (int i_ = 0; i_ < 4; ++i_) {                                     \
            gl16(Kg + kgb[i_] + (unsigned)(kt_) * 256,                       \
                 Kb_ + (w * 4 + i_) * 512);                                  \
            gl16(Vt + vgb[i_] + (unsigned)(kt_),                             \
                 Vb_ + (w * 4 + i_) * 512);                                  \
        }                                                                    \
    } while (0)

    f32x4 O[16];
#pragma unroll
    for (int i = 0; i < 16; ++i) O[i] = f32x4{0.f, 0.f, 0.f, 0.f};
    float mrow = -1e30f, lrow = 0.f;

    // V read base (thread-invariant part)
    const int vbase = (l16 >> 1) * 64 + (l16 & 1) * 32
                    + ((quad ^ ((l16 >> 1) & 3)) * 8);

    STAGE(0, tile0 * 32);

    for (int it = 0; it < ntiles; ++it) {
        asm volatile("s_waitcnt vmcnt(0)" ::: "memory");
        __builtin_amdgcn_s_barrier();
        __builtin_amdgcn_sched_barrier(0);
        if (it + 1 < ntiles) STAGE((it + 1) & 1, (tile0 + it + 1) * 32);
        __builtin_amdgcn_sched_barrier(0);

        const u16* Kc = smem + (it & 1) * 16384;
        const u16* Vc = Kc + 8192;

        f32x4 S[2];
        S[0] = f32x4{0.f, 0.f, 0.f, 0.f};
        S[1] = f32x4{0.f, 0.f, 0.f, 0.f};
        __builtin_amdgcn_s_setprio(1);
#pragma unroll
        for (int kc = 0; kc < 8; ++kc) {
#pragma unroll
            for (int kn = 0; kn < 2; ++kn) {
                const int r2 = kn * 16 + l16;
                const f16x8 kf = *(const f16x8*)
                    &Kc[r2 * 256 + (((kc * 4 + quad) ^ (l16 & 7)) * 8)];
                S[kn] = MFMA_F16(kf, qf[kc], S[kn], 0, 0, 0);
            }
        }
        __builtin_amdgcn_s_setprio(0);

        float mt = fmaxf(fmaxf(fmaxf(S[0][0], S[0][1]), fmaxf(S[0][2], S[0][3])),
                         fmaxf(fmaxf(S[1][0], S[1][1]), fmaxf(S[1][2], S[1][3])));
        mt = fmaxf(mt, __shfl_xor(mt, 16));
        mt = fmaxf(mt, __shfl_xor(mt, 32));
        // T13 defer-max: rescale only when tile max grows past mrow+8.
        if (__any(mt - mrow > 8.f)) {
            const float mnew = fmaxf(mrow, mt);
            const float a = __expf(mrow - mnew);
            lrow *= a;
#pragma unroll
            for (int dv = 0; dv < 16; ++dv)
#pragma unroll
                for (int r = 0; r < 4; ++r) O[dv][r] *= a;
            mrow = mnew;
        }
        f16x8 pfv;
        float s = 0.f;
#pragma unroll
        for (int kn = 0; kn < 2; ++kn)
#pragma unroll
            for (int r = 0; r < 4; ++r) {
                const float e = __expf(S[kn][r] - mrow);
                s += e;
                pfv[kn * 4 + r] = (_Float16)e;
            }
        s += __shfl_xor(s, 16);
        s += __shfl_xor(s, 32);
        lrow += s;

        __builtin_amdgcn_s_setprio(1);
#pragma unroll
        for (int dvt = 0; dvt < 16; ++dvt) {
            const f16x8 vf = *(const f16x8*)&Vc[dvt * 512 + vbase];
            O[dvt] = MFMA_F16(vf, pfv, O[dvt], 0, 0, 0);
        }
        __builtin_amdgcn_s_setprio(0);
    }
#undef STAGE

    __syncthreads();   // all waves done with last tile before smem reuse
    {
        const float rl = 1.0f / lrow;
#pragma unroll
        for (int dvt = 0; dvt < 16; ++dvt) {
            ushort4 h4;
            h4.x = f2h(O[dvt][0] * rl);
            h4.y = f2h(O[dvt][1] * rl);
            h4.z = f2h(O[dvt][2] * rl);
            h4.w = f2h(O[dvt][3] * rl);
            *(ushort4*)&Os[(w * 16 + l16) * 264 + dvt * 16 + quad * 4] = h4;
        }
        if (quad == 0) {
            const int grow = b * 2048 + q0 + w * 16 + l16;
            lmp[z * 16384 + grow]        = lrow;
            lmp[(nz + z) * 16384 + grow] = mrow;
        }
    }
    __syncthreads();

    u16* __restrict__ Oz = Op + (size_t)z * 4194304;
    {
        const int row = t >> 2;
#pragma unroll
        for (int i = 0; i < 8; ++i) {
            const int chunk = (t & 3) * 8 + i;
            *(int4*)&Oz[(size_t)(b * 2048 + q0 + row) * 256 + chunk * 8] =
                *(const int4*)&Os[row * 264 + chunk * 8];
        }
    }
}

// ---------------------------------------------------------------------------
// Kernel 3: combine 2 partials + out projection + LayerNorm + LeakyReLU.
// (R18/R19 structure, measured good — UNCHANGED.)
// ---------------------------------------------------------------------------
__global__ __launch_bounds__(256, 2) void outproj_ln(
    const u16* __restrict__ Op, const float* __restrict__ lmp,
    const u16* __restrict__ Woh, const float* __restrict__ bo,
    const float* __restrict__ gamma, const float* __restrict__ beta,
    float* __restrict__ out)
{
    const int m0   = blockIdx.x * 32;
    const int t    = threadIdx.x;
    const int w    = t >> 6;
    const int rw   = w & 1;        // row-group (16 rows)
    const int cw   = w >> 1;       // col-half (128 cols)
    const int lane = t & 63;
    const int quad = lane >> 4;
    const int l16  = lane & 15;

    __shared__ __align__(16) u16 Ls[32 * 40];
    __shared__ __align__(16) u16 Ws[256 * 40];
    __shared__ _Float16 wls[2][32];
    __shared__ float part[2][16][2][2];   // [rw][row16][cw][{sh,sh2}]

    if (t < 32) {
        const float l0 = lmp[m0 + t],          l1 = lmp[16384 + m0 + t];
        const float mm0 = lmp[32768 + m0 + t], mm1 = lmp[49152 + m0 + t];
        const float mm = fmaxf(mm0, mm1);
        const float u0 = l0 * __expf(mm0 - mm);
        const float u1 = l1 * __expf(mm1 - mm);
        const float inv = 1.0f / (u0 + u1);
        wls[0][t] = (_Float16)(u0 * inv);
        wls[1][t] = (_Float16)(u1 * inv);
    }
    __syncthreads();

    f32x4 acc[8];
#pragma unroll
    for (int i = 0; i < 8; ++i) acc[i] = f32x4{0.f, 0.f, 0.f, 0.f};

    for (int kc = 0; kc < 8; ++kc) {
        if (t < 128) {
            const int row = t >> 2, cg = t & 3;
            const size_t off = (size_t)(m0 + row) * 256 + kc * 32 + cg * 8;
            const f16x8 o0 = __builtin_bit_cast(f16x8, *(const int4*)&Op[off]);
            const f16x8 o1 = __builtin_bit_cast(f16x8, *(const int4*)&Op[4194304 + off]);
            const _Float16 w0 = wls[0][row], w1 = wls[1][row];
            f16x8 lw;
#pragma unroll
            for (int j = 0; j < 8; ++j) lw[j] = o0[j] * w0 + o1[j] * w1;
            *(int4*)&Ls[row * 40 + cg * 8] = __builtin_bit_cast(int4, lw);
        }
#pragma unroll
        for (int i = 0; i < 4; ++i) {
            const int ch = i * 256 + t;
            const int row = ch >> 2, cg = ch & 3;
            *(int4*)&Ws[row * 40 + cg * 8] =
                *(const int4*)&Woh[(size_t)row * 256 + kc * 32 + cg * 8];
        }
        __syncthreads();

        const f16x8 af = *(const f16x8*)&Ls[(rw * 16 + l16) * 40 + quad * 8];
#pragma unroll
        for (int nt = 0; nt < 8; ++nt) {
            const f16x8 bf = *(const f16x8*)&Ws[((cw * 8 + nt) * 16 + l16) * 40 + quad * 8];
            acc[nt] = MFMA_F16(af, bf, acc[nt], 0, 0, 0);
        }
        __syncthreads();
    }

    float g[8], bt[8], bb[8];
#pragma unroll
    for (int nt = 0; nt < 8; ++nt) {
        const int col = cw * 128 + nt * 16 + l16;
        bb[nt] = bo[col]; g[nt] = gamma[col]; bt[nt] = beta[col];
    }

    float shv[4], sh2v[4];
#pragma unroll
    for (int r = 0; r < 4; ++r) {
        float sh = 0.f, sh2 = 0.f;
#pragma unroll
        for (int nt = 0; nt < 8; ++nt) {
            const float h = acc[nt][r] + bb[nt];
            sh  += h;
            sh2 += h * h;
        }
        sh  += __shfl_xor(sh, 1);  sh  += __shfl_xor(sh, 2);
        sh  += __shfl_xor(sh, 4);  sh  += __shfl_xor(sh, 8);
        sh2 += __shfl_xor(sh2, 1); sh2 += __shfl_xor(sh2, 2);
        sh2 += __shfl_xor(sh2, 4); sh2 += __shfl_xor(sh2, 8);
        shv[r] = sh; sh2v[r] = sh2;
    }
    if (l16 == 0) {
#pragma unroll
        for (int r = 0; r < 4; ++r) {
            part[rw][quad * 4 + r][cw][0] = shv[r];
            part[rw][quad * 4 + r][cw][1] = sh2v[r];
        }
    }
    __syncthreads();

#pragma unroll
    for (int r = 0; r < 4; ++r) {
        const float sh  = shv[r]  + part[rw][quad * 4 + r][cw ^ 1][0];
        const float sh2 = sh2v[r] + part[rw][quad * 4 + r][cw ^ 1][1];
        const float mu  = sh * (1.f / 256.f);
        const float var = fmaxf(sh2 * (1.f / 256.f) - mu * mu, 0.f);
        const float rs  = rsqrtf(var + 1e-5f);
        const size_t row = (size_t)(m0 + rw * 16 + quad * 4 + r) * 256;
#pragma unroll
        for (int nt = 0; nt < 8; ++nt) {
            const float hn = (acc[nt][r] + bb[nt] - mu) * rs * g[nt] + bt[nt];
            out[row + cw * 128 + nt * 16 + l16] = (hn >= 0.f) ? hn : 0.01f * hn;
        }
    }
}

// ---------------------------------------------------------------------------
extern "C" void kernel_launch(void* const* d_in, const int* in_sizes, int n_in,
                              void* d_out, int out_size, void* d_ws, size_t ws_size,
                              hipStream_t stream)
{
    const float* x  = (const float*)d_in[0];
    const float* Wq = (const float*)d_in[1];
    const float* bq = (const float*)d_in[2];
    const float* Wk = (const float*)d_in[3];
    const float* bk = (const float*)d_in[4];
    const float* Wv = (const float*)d_in[5];
    const float* bv = (const float*)d_in[6];
    const float* Wo = (const float*)d_in[7];
    const float* bo = (const float*)d_in[8];
    const float* gm = (const float*)d_in[9];
    const float* bt = (const float*)d_in[10];
    float* out = (float*)d_out;

    // ws layout (u16): [W4 262144][Qh 4.19M][Kh 4.19M][Vt 4.19M][Op 2x4.19M][lmp]
    // (identical footprint to the 199µs baseline)
    // Xh (8MB fp16 X) lives in d_out scratch: written by prep_w, read by
    // proj_qkv, overwritten only by outproj_ln at the very end.
    u16* W4 = (u16*)d_ws;
    u16* Qh = W4 + 262144;
    u16* Kh = Qh + 4194304;
    u16* Vt = Kh + 4194304;
    u16* Op = Vt + 4194304;
    float* lmp = (float*)(Op + 2 * 4194304);  // l[2][16384], m[2][16384]
    u16* Woh = W4 + 196608;
    u16* Xh  = (u16*)d_out;

    prep_w     <<<256,            256, 0, stream>>>(Wq, Wk, Wv, Wo, x, W4, Xh);
    proj_qkv   <<<dim3(256, 3),   256, 0, stream>>>(Xh, W4, bq, bk, bv, Qh, Kh, Vt);
    attn       <<<dim3(32, 8, 2), 256, 0, stream>>>(Qh, Kh, Vt, Op, lmp);
    outproj_ln <<<512,            256, 0, stream>>>(Op, lmp, Woh, bo, gm, bt, out);
}